// Round 1
// 688.338 us; speedup vs baseline: 1.3756x; 1.3756x over previous
//
#include <hip/hip_runtime.h>
#include <math.h>

#define T 2048
#define NH 12
#define HD 64
#define C3 2304   // 3*768
#define CE 768
#define NB 2

// ---------------- GEMM: C[M,N] = A[M,K]*B[K,N] + bias[N] ----------------
// BM=BN=64, BK=16, 256 threads, 4x4 microtile. M%64==0, N%64==0, K%16==0.
__global__ __launch_bounds__(256) void gemm_bias_kernel(
        const float* __restrict__ A, const float* __restrict__ B,
        const float* __restrict__ bias, float* __restrict__ Cm,
        int M, int N, int K) {
    __shared__ float As[16][64];   // [k][m]
    __shared__ float Bs[16][68];   // [k][n] (pad)
    const int tid = threadIdx.x;
    const int ty = tid >> 4, tx = tid & 15;
    const int bm = blockIdx.y * 64, bn = blockIdx.x * 64;
    float acc[4][4] = {};
    for (int k0 = 0; k0 < K; k0 += 16) {
        {   // A tile: rows bm..+63, cols k0..+15, store transposed
            int r = tid >> 2;
            int kk = (tid & 3) * 4;
            float4 a = *reinterpret_cast<const float4*>(&A[(size_t)(bm + r) * K + k0 + kk]);
            As[kk + 0][r] = a.x; As[kk + 1][r] = a.y; As[kk + 2][r] = a.z; As[kk + 3][r] = a.w;
        }
        {   // B tile: rows k0..+15, cols bn..+63
            int kk = tid >> 4;
            int c = (tid & 15) * 4;
            *reinterpret_cast<float4*>(&Bs[kk][c]) =
                *reinterpret_cast<const float4*>(&B[(size_t)(k0 + kk) * N + bn + c]);
        }
        __syncthreads();
        #pragma unroll
        for (int kk = 0; kk < 16; ++kk) {
            float4 a4 = *reinterpret_cast<const float4*>(&As[kk][ty * 4]);
            float4 b4 = *reinterpret_cast<const float4*>(&Bs[kk][tx * 4]);
            float av[4] = {a4.x, a4.y, a4.z, a4.w};
            float bv[4] = {b4.x, b4.y, b4.z, b4.w};
            #pragma unroll
            for (int i = 0; i < 4; ++i)
                #pragma unroll
                for (int j = 0; j < 4; ++j)
                    acc[i][j] = fmaf(av[i], bv[j], acc[i][j]);
        }
        __syncthreads();
    }
    #pragma unroll
    for (int i = 0; i < 4; ++i) {
        int row = bm + ty * 4 + i;
        #pragma unroll
        for (int j = 0; j < 4; ++j) {
            int col = bn + tx * 4 + j;
            Cm[(size_t)row * N + col] = acc[i][j] + bias[col];
        }
    }
}

// ---------------- S = masked relu of head-0 scores ----------------
// grid (32 kt, 32 qt, NB), 256 thr; S[b][t][s]
// Transposed LDS operands (Qt[d][t], Kt[d][s]) -> outer product over d,
// conflict-free reads (broadcast + 2-way).
__global__ __launch_bounds__(256) void s0_kernel(const float* __restrict__ qkv,
                                                 float* __restrict__ S) {
    const int kb = blockIdx.x * 64, qb = blockIdx.y * 64, b = blockIdx.z;
    const int tid = threadIdx.x, ty = tid >> 4, tx = tid & 15;
    float* Sb = S + (size_t)b * T * T;
    if (kb > qb) {  // entire tile has s >= t  ->  zero
        #pragma unroll
        for (int i = 0; i < 4; ++i) {
            int row = qb + ty * 4 + i;
            float4 z = {0.f, 0.f, 0.f, 0.f};
            *reinterpret_cast<float4*>(&Sb[(size_t)row * T + kb + tx * 4]) = z;
        }
        return;
    }
    __shared__ float Qt[64][68];   // [d][t]
    __shared__ float Kt[64][68];   // [d][s]
    {
        int r = tid >> 2;
        int c0 = (tid & 3) * 16;
        const float* qrow = qkv + (size_t)(b * T + qb + r) * C3 + 0;    // q head0
        const float* krow = qkv + (size_t)(b * T + kb + r) * C3 + 768;  // k head0
        #pragma unroll
        for (int u = 0; u < 4; ++u) {
            float4 q4 = *reinterpret_cast<const float4*>(&qrow[c0 + u * 4]);
            float4 k4 = *reinterpret_cast<const float4*>(&krow[c0 + u * 4]);
            int d = c0 + u * 4;
            Qt[d + 0][r] = q4.x; Qt[d + 1][r] = q4.y; Qt[d + 2][r] = q4.z; Qt[d + 3][r] = q4.w;
            Kt[d + 0][r] = k4.x; Kt[d + 1][r] = k4.y; Kt[d + 2][r] = k4.z; Kt[d + 3][r] = k4.w;
        }
    }
    __syncthreads();
    float acc[4][4] = {};
    #pragma unroll
    for (int d = 0; d < 64; ++d) {
        float4 qv = *reinterpret_cast<const float4*>(&Qt[d][ty * 4]);
        float4 kv = *reinterpret_cast<const float4*>(&Kt[d][tx * 4]);
        float qa[4] = {qv.x, qv.y, qv.z, qv.w};
        float ka[4] = {kv.x, kv.y, kv.z, kv.w};
        #pragma unroll
        for (int i = 0; i < 4; ++i)
            #pragma unroll
            for (int j = 0; j < 4; ++j)
                acc[i][j] = fmaf(qa[i], ka[j], acc[i][j]);
    }
    #pragma unroll
    for (int i = 0; i < 4; ++i) {
        int t = qb + ty * 4 + i;
        float o[4];
        #pragma unroll
        for (int j = 0; j < 4; ++j) {
            int s = kb + tx * 4 + j;
            float v = acc[i][j] * 0.125f;
            o[j] = (s >= 1 && s < t) ? fmaxf(v, 0.0f) : 0.0f;
        }
        float4 o4 = {o[0], o[1], o[2], o[3]};
        *reinterpret_cast<float4*>(&Sb[(size_t)t * T + kb + tx * 4]) = o4;
    }
}

// ---------------- segmented scan: FF = cumsum_t(S) ----------------
__global__ __launch_bounds__(256) void colsum_kernel(const float* __restrict__ S,
                                                     float* __restrict__ Psum) {
    int s = blockIdx.x * 256 + threadIdx.x;
    int j = blockIdx.y, b = blockIdx.z;
    const float* Sb = S + (size_t)b * T * T;
    float sum = 0.f;
    for (int r = 0; r < 64; ++r) sum += Sb[(size_t)(j * 64 + r) * T + s];
    Psum[((size_t)b * 32 + j) * T + s] = sum;
}

__global__ __launch_bounds__(256) void scanseg_kernel(float* __restrict__ Psum) {
    int s = blockIdx.x * 256 + threadIdx.x;
    int b = blockIdx.y;
    float run = 0.f;
    for (int j = 0; j < 32; ++j) {
        size_t idx = ((size_t)b * 32 + j) * T + s;
        float v = Psum[idx];
        Psum[idx] = run;
        run += v;
    }
}

__global__ __launch_bounds__(256) void ffscan_kernel(float* __restrict__ S,
                                                     const float* __restrict__ Psum) {
    int s = blockIdx.x * 256 + threadIdx.x;
    int j = blockIdx.y, b = blockIdx.z;
    float run = Psum[((size_t)b * 32 + j) * T + s];
    float* Sb = S + (size_t)b * T * T;
    for (int r = 0; r < 64; ++r) {
        size_t idx = (size_t)(j * 64 + r) * T + s;
        run += Sb[idx];
        Sb[idx] = run;
    }
}

// ---------------- flash attention with -FF bias ----------------
// grid (32 qt, NH, NB), 256 thr
// Layout: Qt[d][t], K transposed in KtPs[d][s] (later reused as P[t][s]),
// Vs[s][d]. 52,224 B LDS -> 3 blocks/CU. QK^T = outer product over d:
// Qt read is a 4-addr broadcast, KtPs read is stride-4 (2-way = free).
// qt order reversed so the longest (32-tile) blocks start first.
__global__ __launch_bounds__(256) void flash_kernel(const float* __restrict__ qkv,
                                                    const float* __restrict__ FF,
                                                    float* __restrict__ Y) {
    const int qt = gridDim.x - 1 - blockIdx.x;   // longest first
    const int qb = qt * 64;
    const int h = blockIdx.y, b = blockIdx.z;
    const int tid = threadIdx.x, ty = tid >> 4, tx = tid & 15;
    __shared__ float Qt[64][68];    // [d][t]
    __shared__ float KtPs[64][68];  // K as [d][s], then P as [t][s]
    __shared__ float Vs[64][68];    // [s][d]
    const int r = tid >> 2, c0 = (tid & 3) * 16;
    {
        const float* qrow = qkv + (size_t)(b * T + qb + r) * C3 + h * 64;
        #pragma unroll
        for (int u = 0; u < 4; ++u) {
            float4 q4 = *reinterpret_cast<const float4*>(&qrow[c0 + u * 4]);
            int d = c0 + u * 4;
            Qt[d + 0][r] = q4.x; Qt[d + 1][r] = q4.y; Qt[d + 2][r] = q4.z; Qt[d + 3][r] = q4.w;
        }
    }
    float m[4], l[4], O[4][4];
    #pragma unroll
    for (int i = 0; i < 4; ++i) {
        m[i] = -1e30f; l[i] = 0.f;
        #pragma unroll
        for (int j = 0; j < 4; ++j) O[i][j] = 0.f;
    }
    const float* FFb = FF + (size_t)b * T * T;
    const int nkt = qt + 1;
    for (int kt = 0; kt < nkt; ++kt) {
        const int kb = kt * 64;
        __syncthreads();  // prev PV done reading KtPs/Vs (and Qt visible, iter 0)
        {
            const float* krow = qkv + (size_t)(b * T + kb + r) * C3 + 768 + h * 64;
            const float* vrow = qkv + (size_t)(b * T + kb + r) * C3 + 1536 + h * 64;
            #pragma unroll
            for (int u = 0; u < 4; ++u) {
                float4 k4 = *reinterpret_cast<const float4*>(&krow[c0 + u * 4]);
                int d = c0 + u * 4;
                KtPs[d + 0][r] = k4.x; KtPs[d + 1][r] = k4.y;
                KtPs[d + 2][r] = k4.z; KtPs[d + 3][r] = k4.w;
                *reinterpret_cast<float4*>(&Vs[r][c0 + u * 4]) =
                    *reinterpret_cast<const float4*>(&vrow[c0 + u * 4]);
            }
        }
        __syncthreads();
        // scores = 0.125*QK^T - FF  (masked); outer product over d
        float sc[4][4] = {};
        #pragma unroll
        for (int d = 0; d < 64; ++d) {
            float4 qv = *reinterpret_cast<const float4*>(&Qt[d][ty * 4]);
            float4 kv = *reinterpret_cast<const float4*>(&KtPs[d][tx * 4]);
            float qa[4] = {qv.x, qv.y, qv.z, qv.w};
            float ka[4] = {kv.x, kv.y, kv.z, kv.w};
            #pragma unroll
            for (int i = 0; i < 4; ++i)
                #pragma unroll
                for (int j = 0; j < 4; ++j)
                    sc[i][j] = fmaf(qa[i], ka[j], sc[i][j]);
        }
        #pragma unroll
        for (int i = 0; i < 4; ++i) {
            int t = qb + ty * 4 + i;
            float4 f4 = *reinterpret_cast<const float4*>(&FFb[(size_t)t * T + kb + tx * 4]);
            float fv[4] = {f4.x, f4.y, f4.z, f4.w};
            #pragma unroll
            for (int j = 0; j < 4; ++j) {
                int s = kb + tx * 4 + j;
                float v = sc[i][j] * 0.125f - fv[j];
                sc[i][j] = (s <= t) ? v : -1e30f;
            }
        }
        // online softmax (row reduce across tx = low 4 lane bits)
        #pragma unroll
        for (int i = 0; i < 4; ++i) {
            float tm = fmaxf(fmaxf(sc[i][0], sc[i][1]), fmaxf(sc[i][2], sc[i][3]));
            tm = fmaxf(tm, __shfl_xor(tm, 1));
            tm = fmaxf(tm, __shfl_xor(tm, 2));
            tm = fmaxf(tm, __shfl_xor(tm, 4));
            tm = fmaxf(tm, __shfl_xor(tm, 8));
            float mn = fmaxf(m[i], tm);
            float scale = __expf(m[i] - mn);
            float rs = 0.f;
            #pragma unroll
            for (int j = 0; j < 4; ++j) {
                float p = __expf(sc[i][j] - mn);
                sc[i][j] = p; rs += p;
            }
            rs += __shfl_xor(rs, 1); rs += __shfl_xor(rs, 2);
            rs += __shfl_xor(rs, 4); rs += __shfl_xor(rs, 8);
            l[i] = l[i] * scale + rs;
            m[i] = mn;
            #pragma unroll
            for (int j = 0; j < 4; ++j) O[i][j] *= scale;
        }
        __syncthreads();  // all lanes done reading K before P overwrites it
        #pragma unroll
        for (int i = 0; i < 4; ++i) {
            float4 p4 = {sc[i][0], sc[i][1], sc[i][2], sc[i][3]};
            *reinterpret_cast<float4*>(&KtPs[ty * 4 + i][tx * 4]) = p4;
        }
        __syncthreads();
        // O += P * V   (P reads broadcast over tx; V reads stride-4 = 2-way)
        #pragma unroll
        for (int j4 = 0; j4 < 16; ++j4) {
            float pv[4][4];
            #pragma unroll
            for (int i = 0; i < 4; ++i) {
                float4 t4 = *reinterpret_cast<const float4*>(&KtPs[ty * 4 + i][j4 * 4]);
                pv[i][0] = t4.x; pv[i][1] = t4.y; pv[i][2] = t4.z; pv[i][3] = t4.w;
            }
            #pragma unroll
            for (int jj = 0; jj < 4; ++jj) {
                float4 v4 = *reinterpret_cast<const float4*>(&Vs[j4 * 4 + jj][tx * 4]);
                float vv[4] = {v4.x, v4.y, v4.z, v4.w};
                #pragma unroll
                for (int i = 0; i < 4; ++i)
                    #pragma unroll
                    for (int dd = 0; dd < 4; ++dd)
                        O[i][dd] = fmaf(pv[i][jj], vv[dd], O[i][dd]);
            }
        }
    }
    #pragma unroll
    for (int i = 0; i < 4; ++i) {
        int t = qb + ty * 4 + i;
        float inv = 1.f / l[i];
        float4 o4 = {O[i][0] * inv, O[i][1] * inv, O[i][2] * inv, O[i][3] * inv};
        *reinterpret_cast<float4*>(&Y[(size_t)(b * T + t) * CE + h * 64 + tx * 4]) = o4;
    }
}

extern "C" void kernel_launch(void* const* d_in, const int* in_sizes, int n_in,
                              void* d_out, int out_size, void* d_ws, size_t ws_size,
                              hipStream_t stream) {
    const float* x      = (const float*)d_in[0];
    const float* W_attn = (const float*)d_in[1];
    const float* b_attn = (const float*)d_in[2];
    const float* W_proj = (const float*)d_in[3];
    const float* b_proj = (const float*)d_in[4];
    float* out = (float*)d_out;

    char* ws = (char*)d_ws;
    const size_t QKV_BYTES = (size_t)NB * T * C3 * 4;       // 37,748,736
    const size_t S_BYTES   = (size_t)NB * T * T * 4;        // 33,554,432
    const size_t P_BYTES   = (size_t)NB * 32 * T * 4;       // 524,288
    float* qkv  = (float*)ws;
    float* S    = (float*)(ws + QKV_BYTES);
    float* Psum = (float*)(ws + QKV_BYTES + S_BYTES);
    float* Yb   = (float*)(ws + QKV_BYTES + S_BYTES + P_BYTES);

    const int M = NB * T;  // 4096

    // 1) qkv = x @ W_attn + b_attn
    gemm_bias_kernel<<<dim3(C3 / 64, M / 64), 256, 0, stream>>>(x, W_attn, b_attn, qkv, M, C3, CE);
    // 2) S = masked relu(head0 scores)
    s0_kernel<<<dim3(T / 64, T / 64, NB), 256, 0, stream>>>(qkv, S);
    // 3) FF = cumsum_t(S)  (segmented scan, in place)
    colsum_kernel<<<dim3(T / 256, 32, NB), 256, 0, stream>>>(S, Psum);
    scanseg_kernel<<<dim3(T / 256, NB), 256, 0, stream>>>(Psum);
    ffscan_kernel<<<dim3(T / 256, 32, NB), 256, 0, stream>>>(S, Psum);
    // 4) flash attention with bias -FF
    flash_kernel<<<dim3(T / 64, NH, NB), 256, 0, stream>>>(qkv, S, Yb);
    // 5) out = Y @ W_proj + b_proj
    gemm_bias_kernel<<<dim3(CE / 64, M / 64), 256, 0, stream>>>(Yb, W_proj, b_proj, out, M, CE, CE);
}

// Round 2
// 548.645 us; speedup vs baseline: 1.7259x; 1.2546x over previous
//
#include <hip/hip_runtime.h>
#include <math.h>

#define T 2048
#define NH 12
#define HD 64
#define C3 2304   // 3*768
#define CE 768
#define NB 2

// ---------------- GEMM: C[M,N] = A[M,K]*B[K,N] + bias[N] ----------------
__global__ __launch_bounds__(256) void gemm_bias_kernel(
        const float* __restrict__ A, const float* __restrict__ B,
        const float* __restrict__ bias, float* __restrict__ Cm,
        int M, int N, int K) {
    __shared__ float As[16][64];   // [k][m]
    __shared__ float Bs[16][68];   // [k][n] (pad)
    const int tid = threadIdx.x;
    const int ty = tid >> 4, tx = tid & 15;
    const int bm = blockIdx.y * 64, bn = blockIdx.x * 64;
    float acc[4][4] = {};
    for (int k0 = 0; k0 < K; k0 += 16) {
        {   // A tile: rows bm..+63, cols k0..+15, store transposed
            int r = tid >> 2;
            int kk = (tid & 3) * 4;
            float4 a = *reinterpret_cast<const float4*>(&A[(size_t)(bm + r) * K + k0 + kk]);
            As[kk + 0][r] = a.x; As[kk + 1][r] = a.y; As[kk + 2][r] = a.z; As[kk + 3][r] = a.w;
        }
        {   // B tile: rows k0..+15, cols bn..+63
            int kk = tid >> 4;
            int c = (tid & 15) * 4;
            *reinterpret_cast<float4*>(&Bs[kk][c]) =
                *reinterpret_cast<const float4*>(&B[(size_t)(k0 + kk) * N + bn + c]);
        }
        __syncthreads();
        #pragma unroll
        for (int kk = 0; kk < 16; ++kk) {
            float4 a4 = *reinterpret_cast<const float4*>(&As[kk][ty * 4]);
            float4 b4 = *reinterpret_cast<const float4*>(&Bs[kk][tx * 4]);
            float av[4] = {a4.x, a4.y, a4.z, a4.w};
            float bv[4] = {b4.x, b4.y, b4.z, b4.w};
            #pragma unroll
            for (int i = 0; i < 4; ++i)
                #pragma unroll
                for (int j = 0; j < 4; ++j)
                    acc[i][j] = fmaf(av[i], bv[j], acc[i][j]);
        }
        __syncthreads();
    }
    #pragma unroll
    for (int i = 0; i < 4; ++i) {
        int row = bm + ty * 4 + i;
        #pragma unroll
        for (int j = 0; j < 4; ++j) {
            int col = bn + tx * 4 + j;
            Cm[(size_t)row * N + col] = acc[i][j] + bias[col];
        }
    }
}

// ---------------- S = masked relu of head-0 scores ----------------
__global__ __launch_bounds__(256) void s0_kernel(const float* __restrict__ qkv,
                                                 float* __restrict__ S) {
    const int kb = blockIdx.x * 64, qb = blockIdx.y * 64, b = blockIdx.z;
    const int tid = threadIdx.x, ty = tid >> 4, tx = tid & 15;
    float* Sb = S + (size_t)b * T * T;
    if (kb > qb) {  // entire tile has s >= t  ->  zero
        #pragma unroll
        for (int i = 0; i < 4; ++i) {
            int row = qb + ty * 4 + i;
            float4 z = {0.f, 0.f, 0.f, 0.f};
            *reinterpret_cast<float4*>(&Sb[(size_t)row * T + kb + tx * 4]) = z;
        }
        return;
    }
    __shared__ float Qt[64][68];   // [d][t]
    __shared__ float Kt[64][68];   // [d][s]
    {
        int r = tid >> 2;
        int c0 = (tid & 3) * 16;
        const float* qrow = qkv + (size_t)(b * T + qb + r) * C3 + 0;    // q head0
        const float* krow = qkv + (size_t)(b * T + kb + r) * C3 + 768;  // k head0
        #pragma unroll
        for (int u = 0; u < 4; ++u) {
            float4 q4 = *reinterpret_cast<const float4*>(&qrow[c0 + u * 4]);
            float4 k4 = *reinterpret_cast<const float4*>(&krow[c0 + u * 4]);
            int d = c0 + u * 4;
            Qt[d + 0][r] = q4.x; Qt[d + 1][r] = q4.y; Qt[d + 2][r] = q4.z; Qt[d + 3][r] = q4.w;
            Kt[d + 0][r] = k4.x; Kt[d + 1][r] = k4.y; Kt[d + 2][r] = k4.z; Kt[d + 3][r] = k4.w;
        }
    }
    __syncthreads();
    float acc[4][4] = {};
    #pragma unroll
    for (int d = 0; d < 64; ++d) {
        float4 qv = *reinterpret_cast<const float4*>(&Qt[d][ty * 4]);
        float4 kv = *reinterpret_cast<const float4*>(&Kt[d][tx * 4]);
        float qa[4] = {qv.x, qv.y, qv.z, qv.w};
        float ka[4] = {kv.x, kv.y, kv.z, kv.w};
        #pragma unroll
        for (int i = 0; i < 4; ++i)
            #pragma unroll
            for (int j = 0; j < 4; ++j)
                acc[i][j] = fmaf(qa[i], ka[j], acc[i][j]);
    }
    #pragma unroll
    for (int i = 0; i < 4; ++i) {
        int t = qb + ty * 4 + i;
        float o[4];
        #pragma unroll
        for (int j = 0; j < 4; ++j) {
            int s = kb + tx * 4 + j;
            float v = acc[i][j] * 0.125f;
            o[j] = (s >= 1 && s < t) ? fmaxf(v, 0.0f) : 0.0f;
        }
        float4 o4 = {o[0], o[1], o[2], o[3]};
        *reinterpret_cast<float4*>(&Sb[(size_t)t * T + kb + tx * 4]) = o4;
    }
}

// ---------------- segmented scan: FF = cumsum_t(S) ----------------
__global__ __launch_bounds__(256) void colsum_kernel(const float* __restrict__ S,
                                                     float* __restrict__ Psum) {
    int s = blockIdx.x * 256 + threadIdx.x;
    int j = blockIdx.y, b = blockIdx.z;
    const float* Sb = S + (size_t)b * T * T;
    float sum = 0.f;
    for (int r = 0; r < 64; ++r) sum += Sb[(size_t)(j * 64 + r) * T + s];
    Psum[((size_t)b * 32 + j) * T + s] = sum;
}

__global__ __launch_bounds__(256) void scanseg_kernel(float* __restrict__ Psum) {
    int s = blockIdx.x * 256 + threadIdx.x;
    int b = blockIdx.y;
    float run = 0.f;
    for (int j = 0; j < 32; ++j) {
        size_t idx = ((size_t)b * 32 + j) * T + s;
        float v = Psum[idx];
        Psum[idx] = run;
        run += v;
    }
}

__global__ __launch_bounds__(256) void ffscan_kernel(float* __restrict__ S,
                                                     const float* __restrict__ Psum) {
    int s = blockIdx.x * 256 + threadIdx.x;
    int j = blockIdx.y, b = blockIdx.z;
    float run = Psum[((size_t)b * 32 + j) * T + s];
    float* Sb = S + (size_t)b * T * T;
    for (int r = 0; r < 64; ++r) {
        size_t idx = (size_t)(j * 64 + r) * T + s;
        run += Sb[idx];
        Sb[idx] = run;
    }
}

// ---------------- flash attention with -FF bias, split-K load balance ----------------
// split==1: grid (NB*NH, 48). blockIdx.y = task slot u, size-descending:
//   u in [0,16):  qt = 16+u, k-tiles [0,16)    -> partial set 0   (16 tiles)
//   u in [16,32): qt = 31-u, k-tiles [0,qt+1)  -> direct Y        (16..1 tiles)
//   u in [32,48): qt = 63-u, k-tiles [16,qt+1) -> partial set 1   (16..1 tiles)
// x-fastest dispatch => globally big-tasks-first; 1152 tasks > 768 residency
// slots => hardware backfill balances the triangular workload.
// split==0 fallback (small ws): grid (NB*NH, 32), all direct.
__global__ __launch_bounds__(256) void flash_kernel(const float* __restrict__ qkv,
                                                    const float* __restrict__ FF,
                                                    float* __restrict__ Y,
                                                    float* __restrict__ PO,
                                                    float* __restrict__ PML,
                                                    int split) {
    const int hb = blockIdx.x;
    const int h = hb % NH, b = hb / NH;
    int qt, kt0, kt1, mode;   // mode: 0=direct, 1=partial set0, 2=partial set1
    if (split) {
        const int u = blockIdx.y;
        if (u < 16)      { qt = 16 + u; kt0 = 0;  kt1 = 16;     mode = 1; }
        else if (u < 32) { qt = 31 - u; kt0 = 0;  kt1 = qt + 1; mode = 0; }
        else             { qt = 63 - u; kt0 = 16; kt1 = qt + 1; mode = 2; }
    } else {
        qt = 31 - blockIdx.y; kt0 = 0; kt1 = qt + 1; mode = 0;
    }
    const int qb = qt * 64;
    const int tid = threadIdx.x, ty = tid >> 4, tx = tid & 15;
    __shared__ float Qt[64][68];    // [d][t]
    __shared__ float KtPs[64][68];  // K as [d][s], then P as [t][s]
    __shared__ float Vs[64][68];    // [s][d]
    const int r = tid >> 2, c0 = (tid & 3) * 16;
    {
        const float* qrow = qkv + (size_t)(b * T + qb + r) * C3 + h * 64;
        #pragma unroll
        for (int u = 0; u < 4; ++u) {
            float4 q4 = *reinterpret_cast<const float4*>(&qrow[c0 + u * 4]);
            int d = c0 + u * 4;
            Qt[d + 0][r] = q4.x; Qt[d + 1][r] = q4.y; Qt[d + 2][r] = q4.z; Qt[d + 3][r] = q4.w;
        }
    }
    float m[4], l[4], O[4][4];
    #pragma unroll
    for (int i = 0; i < 4; ++i) {
        m[i] = -1e30f; l[i] = 0.f;
        #pragma unroll
        for (int j = 0; j < 4; ++j) O[i][j] = 0.f;
    }
    const float* FFb = FF + (size_t)b * T * T;
    for (int kt = kt0; kt < kt1; ++kt) {
        const int kb = kt * 64;
        __syncthreads();  // prev PV done reading KtPs/Vs (and Qt visible, iter 0)
        {
            const float* krow = qkv + (size_t)(b * T + kb + r) * C3 + 768 + h * 64;
            const float* vrow = qkv + (size_t)(b * T + kb + r) * C3 + 1536 + h * 64;
            #pragma unroll
            for (int u = 0; u < 4; ++u) {
                float4 k4 = *reinterpret_cast<const float4*>(&krow[c0 + u * 4]);
                int d = c0 + u * 4;
                KtPs[d + 0][r] = k4.x; KtPs[d + 1][r] = k4.y;
                KtPs[d + 2][r] = k4.z; KtPs[d + 3][r] = k4.w;
                *reinterpret_cast<float4*>(&Vs[r][c0 + u * 4]) =
                    *reinterpret_cast<const float4*>(&vrow[c0 + u * 4]);
            }
        }
        __syncthreads();
        // scores = 0.125*QK^T - FF  (masked); outer product over d
        float sc[4][4] = {};
        #pragma unroll
        for (int d = 0; d < 64; ++d) {
            float4 qv = *reinterpret_cast<const float4*>(&Qt[d][ty * 4]);
            float4 kv = *reinterpret_cast<const float4*>(&KtPs[d][tx * 4]);
            float qa[4] = {qv.x, qv.y, qv.z, qv.w};
            float ka[4] = {kv.x, kv.y, kv.z, kv.w};
            #pragma unroll
            for (int i = 0; i < 4; ++i)
                #pragma unroll
                for (int j = 0; j < 4; ++j)
                    sc[i][j] = fmaf(qa[i], ka[j], sc[i][j]);
        }
        #pragma unroll
        for (int i = 0; i < 4; ++i) {
            int t = qb + ty * 4 + i;
            float4 f4 = *reinterpret_cast<const float4*>(&FFb[(size_t)t * T + kb + tx * 4]);
            float fv[4] = {f4.x, f4.y, f4.z, f4.w};
            #pragma unroll
            for (int j = 0; j < 4; ++j) {
                int s = kb + tx * 4 + j;
                float v = sc[i][j] * 0.125f - fv[j];
                sc[i][j] = (s <= t) ? v : -1e30f;
            }
        }
        // online softmax (row reduce across tx = low 4 lane bits)
        #pragma unroll
        for (int i = 0; i < 4; ++i) {
            float tm = fmaxf(fmaxf(sc[i][0], sc[i][1]), fmaxf(sc[i][2], sc[i][3]));
            tm = fmaxf(tm, __shfl_xor(tm, 1));
            tm = fmaxf(tm, __shfl_xor(tm, 2));
            tm = fmaxf(tm, __shfl_xor(tm, 4));
            tm = fmaxf(tm, __shfl_xor(tm, 8));
            float mn = fmaxf(m[i], tm);
            float scale = __expf(m[i] - mn);
            float rs = 0.f;
            #pragma unroll
            for (int j = 0; j < 4; ++j) {
                float p = __expf(sc[i][j] - mn);
                sc[i][j] = p; rs += p;
            }
            rs += __shfl_xor(rs, 1); rs += __shfl_xor(rs, 2);
            rs += __shfl_xor(rs, 4); rs += __shfl_xor(rs, 8);
            l[i] = l[i] * scale + rs;
            m[i] = mn;
            #pragma unroll
            for (int j = 0; j < 4; ++j) O[i][j] *= scale;
        }
        __syncthreads();  // all lanes done reading K before P overwrites it
        #pragma unroll
        for (int i = 0; i < 4; ++i) {
            float4 p4 = {sc[i][0], sc[i][1], sc[i][2], sc[i][3]};
            *reinterpret_cast<float4*>(&KtPs[ty * 4 + i][tx * 4]) = p4;
        }
        __syncthreads();
        // O += P * V   (P reads broadcast over tx; V reads stride-4 = 2-way)
        #pragma unroll
        for (int j4 = 0; j4 < 16; ++j4) {
            float pv[4][4];
            #pragma unroll
            for (int i = 0; i < 4; ++i) {
                float4 t4 = *reinterpret_cast<const float4*>(&KtPs[ty * 4 + i][j4 * 4]);
                pv[i][0] = t4.x; pv[i][1] = t4.y; pv[i][2] = t4.z; pv[i][3] = t4.w;
            }
            #pragma unroll
            for (int jj = 0; jj < 4; ++jj) {
                float4 v4 = *reinterpret_cast<const float4*>(&Vs[j4 * 4 + jj][tx * 4]);
                float vv[4] = {v4.x, v4.y, v4.z, v4.w};
                #pragma unroll
                for (int i = 0; i < 4; ++i)
                    #pragma unroll
                    for (int dd = 0; dd < 4; ++dd)
                        O[i][dd] = fmaf(pv[i][jj], vv[dd], O[i][dd]);
            }
        }
    }
    if (mode == 0) {
        #pragma unroll
        for (int i = 0; i < 4; ++i) {
            int t = qb + ty * 4 + i;
            float inv = 1.f / l[i];
            float4 o4 = {O[i][0] * inv, O[i][1] * inv, O[i][2] * inv, O[i][3] * inv};
            *reinterpret_cast<float4*>(&Y[(size_t)(b * T + t) * CE + h * 64 + tx * 4]) = o4;
        }
    } else {
        const int pidx = (b * NH + h) * 16 + (qt - 16);
        float* Ob  = PO  + (size_t)(mode - 1) * (NB * NH * 16 * 4096) + (size_t)pidx * 4096;
        float* mlb = PML + (size_t)(mode - 1) * (NB * NH * 16 * 128)  + (size_t)pidx * 128;
        #pragma unroll
        for (int i = 0; i < 4; ++i) {
            int rr = ty * 4 + i;
            float4 o4 = {O[i][0], O[i][1], O[i][2], O[i][3]};
            *reinterpret_cast<float4*>(&Ob[rr * 64 + tx * 4]) = o4;   // unnormalized
            if (tx == 0) { mlb[rr] = m[i]; mlb[64 + rr] = l[i]; }
        }
    }
}

// ---------------- merge the two split-K partials for qt >= 16 ----------------
__global__ __launch_bounds__(256) void merge_kernel(const float* __restrict__ PO,
                                                    const float* __restrict__ PML,
                                                    float* __restrict__ Y) {
    const int p = blockIdx.x;           // (b*NH + h)*16 + (qt-16)
    const int q16 = p & 15;
    const int hb = p >> 4;
    const int h = hb % NH, b = hb / NH;
    const int qt = 16 + q16;
    const float* O0  = PO  + (size_t)p * 4096;
    const float* O1  = PO  + (size_t)(NB * NH * 16) * 4096 + (size_t)p * 4096;
    const float* ml0 = PML + (size_t)p * 128;
    const float* ml1 = PML + (size_t)(NB * NH * 16) * 128  + (size_t)p * 128;
    const int tid = threadIdx.x;
    const int r = tid >> 2, c0 = (tid & 3) * 16;
    float m0 = ml0[r], l0 = ml0[64 + r];
    float m1 = ml1[r], l1 = ml1[64 + r];
    float M  = fmaxf(m0, m1);
    float a0 = __expf(m0 - M), a1 = __expf(m1 - M);
    float inv = 1.f / (a0 * l0 + a1 * l1);
    const int t = qt * 64 + r;
    float* Yrow = Y + (size_t)(b * T + t) * CE + h * 64;
    #pragma unroll
    for (int u = 0; u < 4; ++u) {
        float4 x0 = *reinterpret_cast<const float4*>(&O0[r * 64 + c0 + u * 4]);
        float4 x1 = *reinterpret_cast<const float4*>(&O1[r * 64 + c0 + u * 4]);
        float4 y;
        y.x = (a0 * x0.x + a1 * x1.x) * inv;
        y.y = (a0 * x0.y + a1 * x1.y) * inv;
        y.z = (a0 * x0.z + a1 * x1.z) * inv;
        y.w = (a0 * x0.w + a1 * x1.w) * inv;
        *reinterpret_cast<float4*>(&Yrow[c0 + u * 4]) = y;
    }
}

extern "C" void kernel_launch(void* const* d_in, const int* in_sizes, int n_in,
                              void* d_out, int out_size, void* d_ws, size_t ws_size,
                              hipStream_t stream) {
    const float* x      = (const float*)d_in[0];
    const float* W_attn = (const float*)d_in[1];
    const float* b_attn = (const float*)d_in[2];
    const float* W_proj = (const float*)d_in[3];
    const float* b_proj = (const float*)d_in[4];
    float* out = (float*)d_out;

    char* ws = (char*)d_ws;
    const size_t QKV_BYTES = (size_t)NB * T * C3 * 4;       // 37,748,736
    const size_t S_BYTES   = (size_t)NB * T * T * 4;        // 33,554,432
    const size_t P_BYTES   = (size_t)NB * 32 * T * 4;       //    524,288
    const size_t Y_BYTES   = (size_t)NB * T * CE * 4;       // 12,582,912
    const size_t PO_BYTES  = (size_t)2 * NB * NH * 16 * 4096 * 4;  // 12,582,912
    const size_t PML_BYTES = (size_t)2 * NB * NH * 16 * 128 * 4;   //    393,216
    float* qkv  = (float*)ws;
    float* S    = (float*)(ws + QKV_BYTES);
    float* Psum = (float*)(ws + QKV_BYTES + S_BYTES);
    float* Yb   = (float*)(ws + QKV_BYTES + S_BYTES + P_BYTES);
    float* PO   = (float*)(ws + QKV_BYTES + S_BYTES + P_BYTES + Y_BYTES);
    float* PML  = (float*)(ws + QKV_BYTES + S_BYTES + P_BYTES + Y_BYTES + PO_BYTES);
    const size_t NEED = QKV_BYTES + S_BYTES + P_BYTES + Y_BYTES + PO_BYTES + PML_BYTES;
    const int split = (ws_size >= NEED) ? 1 : 0;

    const int M = NB * T;  // 4096

    // 1) qkv = x @ W_attn + b_attn
    gemm_bias_kernel<<<dim3(C3 / 64, M / 64), 256, 0, stream>>>(x, W_attn, b_attn, qkv, M, C3, CE);
    // 2) S = masked relu(head0 scores)
    s0_kernel<<<dim3(T / 64, T / 64, NB), 256, 0, stream>>>(qkv, S);
    // 3) FF = cumsum_t(S)  (segmented scan, in place)
    colsum_kernel<<<dim3(T / 256, 32, NB), 256, 0, stream>>>(S, Psum);
    scanseg_kernel<<<dim3(T / 256, NB), 256, 0, stream>>>(Psum);
    ffscan_kernel<<<dim3(T / 256, 32, NB), 256, 0, stream>>>(S, Psum);
    // 4) flash attention with bias -FF (split-K balanced if ws allows)
    if (split) {
        flash_kernel<<<dim3(NB * NH, 48), 256, 0, stream>>>(qkv, S, Yb, PO, PML, 1);
        merge_kernel<<<dim3(NB * NH * 16), 256, 0, stream>>>(PO, PML, Yb);
    } else {
        flash_kernel<<<dim3(NB * NH, 32), 256, 0, stream>>>(qkv, S, Yb, PO, PML, 0);
    }
    // 5) out = Y @ W_proj + b_proj
    gemm_bias_kernel<<<dim3(CE / 64, M / 64), 256, 0, stream>>>(Yb, W_proj, b_proj, out, M, CE, CE);
}

// Round 3
// 396.836 us; speedup vs baseline: 2.3861x; 1.3825x over previous
//
#include <hip/hip_runtime.h>
#include <math.h>

#define T 2048
#define NH 12
#define HD 64
#define C3 2304   // 3*768
#define CE 768
#define NB 2

typedef __attribute__((ext_vector_type(8))) short bf16x8;
typedef __attribute__((ext_vector_type(4))) float f32x4;

// ---------------- fp32 -> (hi,lo) bf16 split, RNE both halves ----------------
__device__ inline void bf16split(float a, unsigned short& h, unsigned short& l) {
    unsigned int u = __float_as_uint(a);
    unsigned int r = (u + 0x7FFFu + ((u >> 16) & 1u)) >> 16;
    h = (unsigned short)r;
    float hf = __uint_as_float(r << 16);
    float lo = a - hf;                      // exact (Sterbenz)
    unsigned int v = __float_as_uint(lo);
    l = (unsigned short)((v + 0x7FFFu + ((v >> 16) & 1u)) >> 16);
}

// A-side converter: fp32 [R][C] -> bf16 planes H,L (same layout). total/8 threads.
__global__ __launch_bounds__(256) void cvt_split_kernel(const float* __restrict__ A,
        unsigned short* __restrict__ H, unsigned short* __restrict__ L) {
    int i = blockIdx.x * 256 + threadIdx.x;         // 8-element group
    float4 a0 = *(reinterpret_cast<const float4*>(A) + (size_t)i * 2);
    float4 a1 = *(reinterpret_cast<const float4*>(A) + (size_t)i * 2 + 1);
    float f[8] = {a0.x, a0.y, a0.z, a0.w, a1.x, a1.y, a1.z, a1.w};
    unsigned short h[8], l[8];
    #pragma unroll
    for (int j = 0; j < 8; ++j) bf16split(f[j], h[j], l[j]);
    uint4 hv, lv;
    hv.x = (unsigned)h[0] | ((unsigned)h[1] << 16); hv.y = (unsigned)h[2] | ((unsigned)h[3] << 16);
    hv.z = (unsigned)h[4] | ((unsigned)h[5] << 16); hv.w = (unsigned)h[6] | ((unsigned)h[7] << 16);
    lv.x = (unsigned)l[0] | ((unsigned)l[1] << 16); lv.y = (unsigned)l[2] | ((unsigned)l[3] << 16);
    lv.z = (unsigned)l[4] | ((unsigned)l[5] << 16); lv.w = (unsigned)l[6] | ((unsigned)l[7] << 16);
    reinterpret_cast<uint4*>(H)[i] = hv;
    reinterpret_cast<uint4*>(L)[i] = lv;
}

// B-side converter with transpose: fp32 W[K][N] -> bf16 planes [N][K].
// grid (N/64, K/64)
__global__ __launch_bounds__(256) void cvt_split_T_kernel(const float* __restrict__ W,
        unsigned short* __restrict__ H, unsigned short* __restrict__ L, int K, int N) {
    __shared__ float tile[64][65];
    const int n0 = blockIdx.x * 64, k0 = blockIdx.y * 64;
    const int t = threadIdx.x;
    {
        int r = t >> 2, c4 = (t & 3) * 16;
        #pragma unroll
        for (int u = 0; u < 4; ++u) {
            float4 w = *reinterpret_cast<const float4*>(&W[(size_t)(k0 + r) * N + n0 + c4 + u * 4]);
            tile[r][c4 + u * 4 + 0] = w.x; tile[r][c4 + u * 4 + 1] = w.y;
            tile[r][c4 + u * 4 + 2] = w.z; tile[r][c4 + u * 4 + 3] = w.w;
        }
    }
    __syncthreads();
    {
        int n = t >> 2, kc = (t & 3) * 16;
        unsigned short h[16], l[16];
        #pragma unroll
        for (int j = 0; j < 16; ++j) bf16split(tile[kc + j][n], h[j], l[j]);
        uint4 hv0, hv1, lv0, lv1;
        hv0.x = (unsigned)h[0] | ((unsigned)h[1] << 16);  hv0.y = (unsigned)h[2] | ((unsigned)h[3] << 16);
        hv0.z = (unsigned)h[4] | ((unsigned)h[5] << 16);  hv0.w = (unsigned)h[6] | ((unsigned)h[7] << 16);
        hv1.x = (unsigned)h[8] | ((unsigned)h[9] << 16);  hv1.y = (unsigned)h[10] | ((unsigned)h[11] << 16);
        hv1.z = (unsigned)h[12] | ((unsigned)h[13] << 16); hv1.w = (unsigned)h[14] | ((unsigned)h[15] << 16);
        lv0.x = (unsigned)l[0] | ((unsigned)l[1] << 16);  lv0.y = (unsigned)l[2] | ((unsigned)l[3] << 16);
        lv0.z = (unsigned)l[4] | ((unsigned)l[5] << 16);  lv0.w = (unsigned)l[6] | ((unsigned)l[7] << 16);
        lv1.x = (unsigned)l[8] | ((unsigned)l[9] << 16);  lv1.y = (unsigned)l[10] | ((unsigned)l[11] << 16);
        lv1.z = (unsigned)l[12] | ((unsigned)l[13] << 16); lv1.w = (unsigned)l[14] | ((unsigned)l[15] << 16);
        size_t o = (size_t)(n0 + n) * K + k0 + kc;
        reinterpret_cast<uint4*>(&H[o])[0] = hv0; reinterpret_cast<uint4*>(&H[o])[1] = hv1;
        reinterpret_cast<uint4*>(&L[o])[0] = lv0; reinterpret_cast<uint4*>(&L[o])[1] = lv1;
    }
}

// ---------------- split-bf16 MFMA GEMM: C = A*B + bias ----------------
// A planes [M][K] (hi,lo), B planes [N][K] (hi,lo). BM=BN=128, BK=32.
// 256 thr = 4 waves, each wave 64x64 = 4x4 fragments of 16x16x32.
// 3 MFMAs per fragment pair: Ah*Bh + Ah*Bl + Al*Bh  (~fp32 accuracy).
// LDS row stride 40 bf16 (80 B): fragment-read bank starts 20r%32 -> 2-way (free).
#define LDST 40
__global__ __launch_bounds__(256) void gemm_mfma_kernel(
        const unsigned short* __restrict__ Ah, const unsigned short* __restrict__ Al,
        const unsigned short* __restrict__ Bh, const unsigned short* __restrict__ Bl,
        const float* __restrict__ bias, float* __restrict__ Cm,
        int M, int N, int K) {
    __shared__ unsigned short lA[2][128 * LDST];
    __shared__ unsigned short lB[2][128 * LDST];
    const int tid = threadIdx.x;
    const int bm = blockIdx.y * 128, bn = blockIdx.x * 128;
    const int lane = tid & 63, wid = tid >> 6;
    const int wr = wid >> 1, wc = wid & 1;
    f32x4 acc[4][4];
    #pragma unroll
    for (int i = 0; i < 4; ++i)
        #pragma unroll
        for (int j = 0; j < 4; ++j) acc[i][j] = (f32x4){0.f, 0.f, 0.f, 0.f};
    const int srow = tid >> 2, sk8 = (tid & 3) * 8;     // staging coords
    const int arb = wr * 64 + (lane & 15);              // A fragment row base
    const int brb = wc * 64 + (lane & 15);              // B fragment row base (n)
    const int koff = (lane >> 4) * 8;                   // K offset within BK
    for (int k0 = 0; k0 < K; k0 += 32) {
        __syncthreads();
        #pragma unroll
        for (int c = 0; c < 2; ++c) {
            int row = srow + 64 * c;
            uint4 va = *reinterpret_cast<const uint4*>(&Ah[(size_t)(bm + row) * K + k0 + sk8]);
            uint4 vb = *reinterpret_cast<const uint4*>(&Al[(size_t)(bm + row) * K + k0 + sk8]);
            uint4 vc = *reinterpret_cast<const uint4*>(&Bh[(size_t)(bn + row) * K + k0 + sk8]);
            uint4 vd = *reinterpret_cast<const uint4*>(&Bl[(size_t)(bn + row) * K + k0 + sk8]);
            *reinterpret_cast<uint4*>(&lA[0][row * LDST + sk8]) = va;
            *reinterpret_cast<uint4*>(&lA[1][row * LDST + sk8]) = vb;
            *reinterpret_cast<uint4*>(&lB[0][row * LDST + sk8]) = vc;
            *reinterpret_cast<uint4*>(&lB[1][row * LDST + sk8]) = vd;
        }
        __syncthreads();
        bf16x8 fa[2][4], fb[2][4];
        #pragma unroll
        for (int fi = 0; fi < 4; ++fi) {
            fa[0][fi] = *reinterpret_cast<const bf16x8*>(&lA[0][(arb + fi * 16) * LDST + koff]);
            fa[1][fi] = *reinterpret_cast<const bf16x8*>(&lA[1][(arb + fi * 16) * LDST + koff]);
            fb[0][fi] = *reinterpret_cast<const bf16x8*>(&lB[0][(brb + fi * 16) * LDST + koff]);
            fb[1][fi] = *reinterpret_cast<const bf16x8*>(&lB[1][(brb + fi * 16) * LDST + koff]);
        }
        #pragma unroll
        for (int fi = 0; fi < 4; ++fi)
            #pragma unroll
            for (int fj = 0; fj < 4; ++fj) {
                acc[fi][fj] = __builtin_amdgcn_mfma_f32_16x16x32_bf16(fa[0][fi], fb[0][fj], acc[fi][fj], 0, 0, 0);
                acc[fi][fj] = __builtin_amdgcn_mfma_f32_16x16x32_bf16(fa[0][fi], fb[1][fj], acc[fi][fj], 0, 0, 0);
                acc[fi][fj] = __builtin_amdgcn_mfma_f32_16x16x32_bf16(fa[1][fi], fb[0][fj], acc[fi][fj], 0, 0, 0);
            }
    }
    // epilogue: C/D layout col=lane&15, row=(lane>>4)*4+p  [m89-verified]
    #pragma unroll
    for (int fj = 0; fj < 4; ++fj) {
        int col = bn + wc * 64 + fj * 16 + (lane & 15);
        float bv = bias[col];
        #pragma unroll
        for (int fi = 0; fi < 4; ++fi) {
            int row0 = bm + wr * 64 + fi * 16 + (lane >> 4) * 4;
            #pragma unroll
            for (int p = 0; p < 4; ++p)
                Cm[(size_t)(row0 + p) * N + col] = acc[fi][fj][p] + bv;
        }
    }
}

// ---------------- fp32 GEMM fallback (small ws) ----------------
__global__ __launch_bounds__(256) void gemm_bias_kernel(
        const float* __restrict__ A, const float* __restrict__ B,
        const float* __restrict__ bias, float* __restrict__ Cm,
        int M, int N, int K) {
    __shared__ float As[16][64];
    __shared__ float Bs[16][68];
    const int tid = threadIdx.x;
    const int ty = tid >> 4, tx = tid & 15;
    const int bm = blockIdx.y * 64, bn = blockIdx.x * 64;
    float acc[4][4] = {};
    for (int k0 = 0; k0 < K; k0 += 16) {
        {
            int r = tid >> 2;
            int kk = (tid & 3) * 4;
            float4 a = *reinterpret_cast<const float4*>(&A[(size_t)(bm + r) * K + k0 + kk]);
            As[kk + 0][r] = a.x; As[kk + 1][r] = a.y; As[kk + 2][r] = a.z; As[kk + 3][r] = a.w;
        }
        {
            int kk = tid >> 4;
            int c = (tid & 15) * 4;
            *reinterpret_cast<float4*>(&Bs[kk][c]) =
                *reinterpret_cast<const float4*>(&B[(size_t)(k0 + kk) * N + bn + c]);
        }
        __syncthreads();
        #pragma unroll
        for (int kk = 0; kk < 16; ++kk) {
            float4 a4 = *reinterpret_cast<const float4*>(&As[kk][ty * 4]);
            float4 b4 = *reinterpret_cast<const float4*>(&Bs[kk][tx * 4]);
            float av[4] = {a4.x, a4.y, a4.z, a4.w};
            float bv[4] = {b4.x, b4.y, b4.z, b4.w};
            #pragma unroll
            for (int i = 0; i < 4; ++i)
                #pragma unroll
                for (int j = 0; j < 4; ++j)
                    acc[i][j] = fmaf(av[i], bv[j], acc[i][j]);
        }
        __syncthreads();
    }
    #pragma unroll
    for (int i = 0; i < 4; ++i) {
        int row = bm + ty * 4 + i;
        #pragma unroll
        for (int j = 0; j < 4; ++j) {
            int col = bn + tx * 4 + j;
            Cm[(size_t)row * N + col] = acc[i][j] + bias[col];
        }
    }
}

// ---------------- S = masked relu of head-0 scores ----------------
__global__ __launch_bounds__(256) void s0_kernel(const float* __restrict__ qkv,
                                                 float* __restrict__ S) {
    const int kb = blockIdx.x * 64, qb = blockIdx.y * 64, b = blockIdx.z;
    const int tid = threadIdx.x, ty = tid >> 4, tx = tid & 15;
    float* Sb = S + (size_t)b * T * T;
    if (kb > qb) {
        #pragma unroll
        for (int i = 0; i < 4; ++i) {
            int row = qb + ty * 4 + i;
            float4 z = {0.f, 0.f, 0.f, 0.f};
            *reinterpret_cast<float4*>(&Sb[(size_t)row * T + kb + tx * 4]) = z;
        }
        return;
    }
    __shared__ float Qt[64][68];
    __shared__ float Kt[64][68];
    {
        int r = tid >> 2;
        int c0 = (tid & 3) * 16;
        const float* qrow = qkv + (size_t)(b * T + qb + r) * C3 + 0;
        const float* krow = qkv + (size_t)(b * T + kb + r) * C3 + 768;
        #pragma unroll
        for (int u = 0; u < 4; ++u) {
            float4 q4 = *reinterpret_cast<const float4*>(&qrow[c0 + u * 4]);
            float4 k4 = *reinterpret_cast<const float4*>(&krow[c0 + u * 4]);
            int d = c0 + u * 4;
            Qt[d + 0][r] = q4.x; Qt[d + 1][r] = q4.y; Qt[d + 2][r] = q4.z; Qt[d + 3][r] = q4.w;
            Kt[d + 0][r] = k4.x; Kt[d + 1][r] = k4.y; Kt[d + 2][r] = k4.z; Kt[d + 3][r] = k4.w;
        }
    }
    __syncthreads();
    float acc[4][4] = {};
    #pragma unroll
    for (int d = 0; d < 64; ++d) {
        float4 qv = *reinterpret_cast<const float4*>(&Qt[d][ty * 4]);
        float4 kv = *reinterpret_cast<const float4*>(&Kt[d][tx * 4]);
        float qa[4] = {qv.x, qv.y, qv.z, qv.w};
        float ka[4] = {kv.x, kv.y, kv.z, kv.w};
        #pragma unroll
        for (int i = 0; i < 4; ++i)
            #pragma unroll
            for (int j = 0; j < 4; ++j)
                acc[i][j] = fmaf(qa[i], ka[j], acc[i][j]);
    }
    #pragma unroll
    for (int i = 0; i < 4; ++i) {
        int t = qb + ty * 4 + i;
        float o[4];
        #pragma unroll
        for (int j = 0; j < 4; ++j) {
            int s = kb + tx * 4 + j;
            float v = acc[i][j] * 0.125f;
            o[j] = (s >= 1 && s < t) ? fmaxf(v, 0.0f) : 0.0f;
        }
        float4 o4 = {o[0], o[1], o[2], o[3]};
        *reinterpret_cast<float4*>(&Sb[(size_t)t * T + kb + tx * 4]) = o4;
    }
}

// ---------------- segmented scan: FF = cumsum_t(S) ----------------
__global__ __launch_bounds__(256) void colsum_kernel(const float* __restrict__ S,
                                                     float* __restrict__ Psum) {
    int s = blockIdx.x * 256 + threadIdx.x;
    int j = blockIdx.y, b = blockIdx.z;
    const float* Sb = S + (size_t)b * T * T;
    float sum = 0.f;
    for (int r = 0; r < 64; ++r) sum += Sb[(size_t)(j * 64 + r) * T + s];
    Psum[((size_t)b * 32 + j) * T + s] = sum;
}

__global__ __launch_bounds__(256) void scanseg_kernel(float* __restrict__ Psum) {
    int s = blockIdx.x * 256 + threadIdx.x;
    int b = blockIdx.y;
    float run = 0.f;
    for (int j = 0; j < 32; ++j) {
        size_t idx = ((size_t)b * 32 + j) * T + s;
        float v = Psum[idx];
        Psum[idx] = run;
        run += v;
    }
}

__global__ __launch_bounds__(256) void ffscan_kernel(float* __restrict__ S,
                                                     const float* __restrict__ Psum) {
    int s = blockIdx.x * 256 + threadIdx.x;
    int j = blockIdx.y, b = blockIdx.z;
    float run = Psum[((size_t)b * 32 + j) * T + s];
    float* Sb = S + (size_t)b * T * T;
    for (int r = 0; r < 64; ++r) {
        size_t idx = (size_t)(j * 64 + r) * T + s;
        run += Sb[idx];
        Sb[idx] = run;
    }
}

// ---------------- flash attention with -FF bias, split-K load balance ----------------
__global__ __launch_bounds__(256) void flash_kernel(const float* __restrict__ qkv,
                                                    const float* __restrict__ FF,
                                                    float* __restrict__ Y,
                                                    float* __restrict__ PO,
                                                    float* __restrict__ PML,
                                                    int split) {
    const int hb = blockIdx.x;
    const int h = hb % NH, b = hb / NH;
    int qt, kt0, kt1, mode;
    if (split) {
        const int u = blockIdx.y;
        if (u < 16)      { qt = 16 + u; kt0 = 0;  kt1 = 16;     mode = 1; }
        else if (u < 32) { qt = 31 - u; kt0 = 0;  kt1 = qt + 1; mode = 0; }
        else             { qt = 63 - u; kt0 = 16; kt1 = qt + 1; mode = 2; }
    } else {
        qt = 31 - blockIdx.y; kt0 = 0; kt1 = qt + 1; mode = 0;
    }
    const int qb = qt * 64;
    const int tid = threadIdx.x, ty = tid >> 4, tx = tid & 15;
    __shared__ float Qt[64][68];
    __shared__ float KtPs[64][68];
    __shared__ float Vs[64][68];
    const int r = tid >> 2, c0 = (tid & 3) * 16;
    {
        const float* qrow = qkv + (size_t)(b * T + qb + r) * C3 + h * 64;
        #pragma unroll
        for (int u = 0; u < 4; ++u) {
            float4 q4 = *reinterpret_cast<const float4*>(&qrow[c0 + u * 4]);
            int d = c0 + u * 4;
            Qt[d + 0][r] = q4.x; Qt[d + 1][r] = q4.y; Qt[d + 2][r] = q4.z; Qt[d + 3][r] = q4.w;
        }
    }
    float m[4], l[4], O[4][4];
    #pragma unroll
    for (int i = 0; i < 4; ++i) {
        m[i] = -1e30f; l[i] = 0.f;
        #pragma unroll
        for (int j = 0; j < 4; ++j) O[i][j] = 0.f;
    }
    const float* FFb = FF + (size_t)b * T * T;
    for (int kt = kt0; kt < kt1; ++kt) {
        const int kb = kt * 64;
        __syncthreads();
        {
            const float* krow = qkv + (size_t)(b * T + kb + r) * C3 + 768 + h * 64;
            const float* vrow = qkv + (size_t)(b * T + kb + r) * C3 + 1536 + h * 64;
            #pragma unroll
            for (int u = 0; u < 4; ++u) {
                float4 k4 = *reinterpret_cast<const float4*>(&krow[c0 + u * 4]);
                int d = c0 + u * 4;
                KtPs[d + 0][r] = k4.x; KtPs[d + 1][r] = k4.y;
                KtPs[d + 2][r] = k4.z; KtPs[d + 3][r] = k4.w;
                *reinterpret_cast<float4*>(&Vs[r][c0 + u * 4]) =
                    *reinterpret_cast<const float4*>(&vrow[c0 + u * 4]);
            }
        }
        __syncthreads();
        float sc[4][4] = {};
        #pragma unroll
        for (int d = 0; d < 64; ++d) {
            float4 qv = *reinterpret_cast<const float4*>(&Qt[d][ty * 4]);
            float4 kv = *reinterpret_cast<const float4*>(&KtPs[d][tx * 4]);
            float qa[4] = {qv.x, qv.y, qv.z, qv.w};
            float ka[4] = {kv.x, kv.y, kv.z, kv.w};
            #pragma unroll
            for (int i = 0; i < 4; ++i)
                #pragma unroll
                for (int j = 0; j < 4; ++j)
                    sc[i][j] = fmaf(qa[i], ka[j], sc[i][j]);
        }
        #pragma unroll
        for (int i = 0; i < 4; ++i) {
            int t = qb + ty * 4 + i;
            float4 f4 = *reinterpret_cast<const float4*>(&FFb[(size_t)t * T + kb + tx * 4]);
            float fv[4] = {f4.x, f4.y, f4.z, f4.w};
            #pragma unroll
            for (int j = 0; j < 4; ++j) {
                int s = kb + tx * 4 + j;
                float v = sc[i][j] * 0.125f - fv[j];
                sc[i][j] = (s <= t) ? v : -1e30f;
            }
        }
        #pragma unroll
        for (int i = 0; i < 4; ++i) {
            float tm = fmaxf(fmaxf(sc[i][0], sc[i][1]), fmaxf(sc[i][2], sc[i][3]));
            tm = fmaxf(tm, __shfl_xor(tm, 1));
            tm = fmaxf(tm, __shfl_xor(tm, 2));
            tm = fmaxf(tm, __shfl_xor(tm, 4));
            tm = fmaxf(tm, __shfl_xor(tm, 8));
            float mn = fmaxf(m[i], tm);
            float scale = __expf(m[i] - mn);
            float rs = 0.f;
            #pragma unroll
            for (int j = 0; j < 4; ++j) {
                float p = __expf(sc[i][j] - mn);
                sc[i][j] = p; rs += p;
            }
            rs += __shfl_xor(rs, 1); rs += __shfl_xor(rs, 2);
            rs += __shfl_xor(rs, 4); rs += __shfl_xor(rs, 8);
            l[i] = l[i] * scale + rs;
            m[i] = mn;
            #pragma unroll
            for (int j = 0; j < 4; ++j) O[i][j] *= scale;
        }
        __syncthreads();
        #pragma unroll
        for (int i = 0; i < 4; ++i) {
            float4 p4 = {sc[i][0], sc[i][1], sc[i][2], sc[i][3]};
            *reinterpret_cast<float4*>(&KtPs[ty * 4 + i][tx * 4]) = p4;
        }
        __syncthreads();
        #pragma unroll
        for (int j4 = 0; j4 < 16; ++j4) {
            float pv[4][4];
            #pragma unroll
            for (int i = 0; i < 4; ++i) {
                float4 t4 = *reinterpret_cast<const float4*>(&KtPs[ty * 4 + i][j4 * 4]);
                pv[i][0] = t4.x; pv[i][1] = t4.y; pv[i][2] = t4.z; pv[i][3] = t4.w;
            }
            #pragma unroll
            for (int jj = 0; jj < 4; ++jj) {
                float4 v4 = *reinterpret_cast<const float4*>(&Vs[j4 * 4 + jj][tx * 4]);
                float vv[4] = {v4.x, v4.y, v4.z, v4.w};
                #pragma unroll
                for (int i = 0; i < 4; ++i)
                    #pragma unroll
                    for (int dd = 0; dd < 4; ++dd)
                        O[i][dd] = fmaf(pv[i][jj], vv[dd], O[i][dd]);
            }
        }
    }
    if (mode == 0) {
        #pragma unroll
        for (int i = 0; i < 4; ++i) {
            int t = qb + ty * 4 + i;
            float inv = 1.f / l[i];
            float4 o4 = {O[i][0] * inv, O[i][1] * inv, O[i][2] * inv, O[i][3] * inv};
            *reinterpret_cast<float4*>(&Y[(size_t)(b * T + t) * CE + h * 64 + tx * 4]) = o4;
        }
    } else {
        const int pidx = (b * NH + h) * 16 + (qt - 16);
        float* Ob  = PO  + (size_t)(mode - 1) * (NB * NH * 16 * 4096) + (size_t)pidx * 4096;
        float* mlb = PML + (size_t)(mode - 1) * (NB * NH * 16 * 128)  + (size_t)pidx * 128;
        #pragma unroll
        for (int i = 0; i < 4; ++i) {
            int rr = ty * 4 + i;
            float4 o4 = {O[i][0], O[i][1], O[i][2], O[i][3]};
            *reinterpret_cast<float4*>(&Ob[rr * 64 + tx * 4]) = o4;
            if (tx == 0) { mlb[rr] = m[i]; mlb[64 + rr] = l[i]; }
        }
    }
}

// ---------------- merge the two split-K partials for qt >= 16 ----------------
__global__ __launch_bounds__(256) void merge_kernel(const float* __restrict__ PO,
                                                    const float* __restrict__ PML,
                                                    float* __restrict__ Y) {
    const int p = blockIdx.x;
    const int q16 = p & 15;
    const int hb = p >> 4;
    const int h = hb % NH, b = hb / NH;
    const int qt = 16 + q16;
    const float* O0  = PO  + (size_t)p * 4096;
    const float* O1  = PO  + (size_t)(NB * NH * 16) * 4096 + (size_t)p * 4096;
    const float* ml0 = PML + (size_t)p * 128;
    const float* ml1 = PML + (size_t)(NB * NH * 16) * 128  + (size_t)p * 128;
    const int tid = threadIdx.x;
    const int r = tid >> 2, c0 = (tid & 3) * 16;
    float m0 = ml0[r], l0 = ml0[64 + r];
    float m1 = ml1[r], l1 = ml1[64 + r];
    float M  = fmaxf(m0, m1);
    float a0 = __expf(m0 - M), a1 = __expf(m1 - M);
    float inv = 1.f / (a0 * l0 + a1 * l1);
    const int t = qt * 64 + r;
    float* Yrow = Y + (size_t)(b * T + t) * CE + h * 64;
    #pragma unroll
    for (int u = 0; u < 4; ++u) {
        float4 x0 = *reinterpret_cast<const float4*>(&O0[r * 64 + c0 + u * 4]);
        float4 x1 = *reinterpret_cast<const float4*>(&O1[r * 64 + c0 + u * 4]);
        float4 y;
        y.x = (a0 * x0.x + a1 * x1.x) * inv;
        y.y = (a0 * x0.y + a1 * x1.y) * inv;
        y.z = (a0 * x0.z + a1 * x1.z) * inv;
        y.w = (a0 * x0.w + a1 * x1.w) * inv;
        *reinterpret_cast<float4*>(&Yrow[c0 + u * 4]) = y;
    }
}

extern "C" void kernel_launch(void* const* d_in, const int* in_sizes, int n_in,
                              void* d_out, int out_size, void* d_ws, size_t ws_size,
                              hipStream_t stream) {
    const float* x      = (const float*)d_in[0];
    const float* W_attn = (const float*)d_in[1];
    const float* b_attn = (const float*)d_in[2];
    const float* W_proj = (const float*)d_in[3];
    const float* b_proj = (const float*)d_in[4];
    float* out = (float*)d_out;

    char* ws = (char*)d_ws;
    const size_t QKV_BYTES = (size_t)NB * T * C3 * 4;       // 37,748,736
    const size_t S_BYTES   = (size_t)NB * T * T * 4;        // 33,554,432
    const size_t P_BYTES   = (size_t)NB * 32 * T * 4;       //    524,288
    const size_t Y_BYTES   = (size_t)NB * T * CE * 4;       // 12,582,912
    const size_t PO_BYTES  = (size_t)2 * NB * NH * 16 * 4096 * 4;  // 12,582,912
    const size_t PML_BYTES = (size_t)2 * NB * NH * 16 * 128 * 4;   //    393,216
    const size_t PLANE_X   = (size_t)NB * T * CE * 2;       // 6,291,456 (bf16 plane, M*K)
    const size_t PLANE_WA  = (size_t)C3 * CE * 2;           // 3,538,944
    const size_t PLANE_WP  = (size_t)CE * CE * 2;           // 1,179,648

    const size_t U_OFF  = QKV_BYTES + S_BYTES + P_BYTES + Y_BYTES;   // union region
    const size_t U_SIZE = PO_BYTES + PML_BYTES;                      // >= 2*PLANE_X
    const size_t W_OFF  = U_OFF + U_SIZE;

    float* qkv  = (float*)ws;
    float* S    = (float*)(ws + QKV_BYTES);
    float* Psum = (float*)(ws + QKV_BYTES + S_BYTES);
    float* Yb   = (float*)(ws + QKV_BYTES + S_BYTES + P_BYTES);
    float* PO   = (float*)(ws + U_OFF);
    float* PML  = (float*)(ws + U_OFF + PO_BYTES);
    unsigned short* Xh  = (unsigned short*)(ws + U_OFF);             // overlaps PO (dead then)
    unsigned short* Xl  = (unsigned short*)(ws + U_OFF + PLANE_X);
    unsigned short* Yh  = Xh;                                        // reused after merge
    unsigned short* Yl  = Xl;
    unsigned short* WAh = (unsigned short*)(ws + W_OFF);
    unsigned short* WAl = (unsigned short*)(ws + W_OFF + PLANE_WA);
    unsigned short* WPh = (unsigned short*)(ws + W_OFF + 2 * PLANE_WA);
    unsigned short* WPl = (unsigned short*)(ws + W_OFF + 2 * PLANE_WA + PLANE_WP);

    const size_t NEED_SPLIT = U_OFF + U_SIZE;
    const size_t NEED_MFMA  = W_OFF + 2 * PLANE_WA + 2 * PLANE_WP;
    const int split = (ws_size >= NEED_SPLIT) ? 1 : 0;
    const int mfma  = (ws_size >= NEED_MFMA) ? 1 : 0;

    const int M = NB * T;  // 4096

    // 1) qkv = x @ W_attn + b_attn
    if (mfma) {
        cvt_split_T_kernel<<<dim3(C3 / 64, CE / 64), 256, 0, stream>>>(W_attn, WAh, WAl, CE, C3);
        cvt_split_T_kernel<<<dim3(CE / 64, CE / 64), 256, 0, stream>>>(W_proj, WPh, WPl, CE, CE);
        cvt_split_kernel<<<dim3((M * CE / 8) / 256), 256, 0, stream>>>(x, Xh, Xl);
        gemm_mfma_kernel<<<dim3(C3 / 128, M / 128), 256, 0, stream>>>(Xh, Xl, WAh, WAl, b_attn, qkv, M, C3, CE);
    } else {
        gemm_bias_kernel<<<dim3(C3 / 64, M / 64), 256, 0, stream>>>(x, W_attn, b_attn, qkv, M, C3, CE);
    }
    // 2) S = masked relu(head0 scores)
    s0_kernel<<<dim3(T / 64, T / 64, NB), 256, 0, stream>>>(qkv, S);
    // 3) FF = cumsum_t(S)  (segmented scan, in place)
    colsum_kernel<<<dim3(T / 256, 32, NB), 256, 0, stream>>>(S, Psum);
    scanseg_kernel<<<dim3(T / 256, NB), 256, 0, stream>>>(Psum);
    ffscan_kernel<<<dim3(T / 256, 32, NB), 256, 0, stream>>>(S, Psum);
    // 4) flash attention with bias -FF (split-K balanced if ws allows)
    if (split) {
        flash_kernel<<<dim3(NB * NH, 48), 256, 0, stream>>>(qkv, S, Yb, PO, PML, 1);
        merge_kernel<<<dim3(NB * NH * 16), 256, 0, stream>>>(PO, PML, Yb);
    } else {
        flash_kernel<<<dim3(NB * NH, 32), 256, 0, stream>>>(qkv, S, Yb, PO, PML, 0);
    }
    // 5) out = Y @ W_proj + b_proj
    if (mfma) {
        cvt_split_kernel<<<dim3((M * CE / 8) / 256), 256, 0, stream>>>(Yb, Yh, Yl);
        gemm_mfma_kernel<<<dim3(CE / 128, M / 128), 256, 0, stream>>>(Yh, Yl, WPh, WPl, b_proj, out, M, CE, CE);
    } else {
        gemm_bias_kernel<<<dim3(CE / 64, M / 64), 256, 0, stream>>>(Yb, W_proj, b_proj, out, M, CE, CE);
    }
}

// Round 4
// 293.197 us; speedup vs baseline: 3.2295x; 1.3535x over previous
//
#include <hip/hip_runtime.h>
#include <math.h>

#define T 2048
#define NH 12
#define HD 64
#define C3 2304   // 3*768
#define CE 768
#define NB 2

typedef __attribute__((ext_vector_type(8))) short bf16x8;
typedef __attribute__((ext_vector_type(4))) float f32x4;

// ---------------- fp32 -> (hi,lo) bf16 split, RNE both halves ----------------
__device__ inline void bf16split(float a, unsigned short& h, unsigned short& l) {
    unsigned int u = __float_as_uint(a);
    unsigned int r = (u + 0x7FFFu + ((u >> 16) & 1u)) >> 16;
    h = (unsigned short)r;
    float hf = __uint_as_float(r << 16);
    float lo = a - hf;                      // exact (Sterbenz)
    unsigned int v = __float_as_uint(lo);
    l = (unsigned short)((v + 0x7FFFu + ((v >> 16) & 1u)) >> 16);
}

// A-side converter: fp32 [R][C] -> bf16 planes H,L (same layout). total/8 threads.
__global__ __launch_bounds__(256) void cvt_split_kernel(const float* __restrict__ A,
        unsigned short* __restrict__ H, unsigned short* __restrict__ L) {
    int i = blockIdx.x * 256 + threadIdx.x;         // 8-element group
    float4 a0 = *(reinterpret_cast<const float4*>(A) + (size_t)i * 2);
    float4 a1 = *(reinterpret_cast<const float4*>(A) + (size_t)i * 2 + 1);
    float f[8] = {a0.x, a0.y, a0.z, a0.w, a1.x, a1.y, a1.z, a1.w};
    unsigned short h[8], l[8];
    #pragma unroll
    for (int j = 0; j < 8; ++j) bf16split(f[j], h[j], l[j]);
    uint4 hv, lv;
    hv.x = (unsigned)h[0] | ((unsigned)h[1] << 16); hv.y = (unsigned)h[2] | ((unsigned)h[3] << 16);
    hv.z = (unsigned)h[4] | ((unsigned)h[5] << 16); hv.w = (unsigned)h[6] | ((unsigned)h[7] << 16);
    lv.x = (unsigned)l[0] | ((unsigned)l[1] << 16); lv.y = (unsigned)l[2] | ((unsigned)l[3] << 16);
    lv.z = (unsigned)l[4] | ((unsigned)l[5] << 16); lv.w = (unsigned)l[6] | ((unsigned)l[7] << 16);
    reinterpret_cast<uint4*>(H)[i] = hv;
    reinterpret_cast<uint4*>(L)[i] = lv;
}

// B-side converter with transpose: fp32 W[K][N] -> bf16 planes [N][K].
__global__ __launch_bounds__(256) void cvt_split_T_kernel(const float* __restrict__ W,
        unsigned short* __restrict__ H, unsigned short* __restrict__ L, int K, int N) {
    __shared__ float tile[64][65];
    const int n0 = blockIdx.x * 64, k0 = blockIdx.y * 64;
    const int t = threadIdx.x;
    {
        int r = t >> 2, c4 = (t & 3) * 16;
        #pragma unroll
        for (int u = 0; u < 4; ++u) {
            float4 w = *reinterpret_cast<const float4*>(&W[(size_t)(k0 + r) * N + n0 + c4 + u * 4]);
            tile[r][c4 + u * 4 + 0] = w.x; tile[r][c4 + u * 4 + 1] = w.y;
            tile[r][c4 + u * 4 + 2] = w.z; tile[r][c4 + u * 4 + 3] = w.w;
        }
    }
    __syncthreads();
    {
        int n = t >> 2, kc = (t & 3) * 16;
        unsigned short h[16], l[16];
        #pragma unroll
        for (int j = 0; j < 16; ++j) bf16split(tile[kc + j][n], h[j], l[j]);
        uint4 hv0, hv1, lv0, lv1;
        hv0.x = (unsigned)h[0] | ((unsigned)h[1] << 16);  hv0.y = (unsigned)h[2] | ((unsigned)h[3] << 16);
        hv0.z = (unsigned)h[4] | ((unsigned)h[5] << 16);  hv0.w = (unsigned)h[6] | ((unsigned)h[7] << 16);
        hv1.x = (unsigned)h[8] | ((unsigned)h[9] << 16);  hv1.y = (unsigned)h[10] | ((unsigned)h[11] << 16);
        hv1.z = (unsigned)h[12] | ((unsigned)h[13] << 16); hv1.w = (unsigned)h[14] | ((unsigned)h[15] << 16);
        lv0.x = (unsigned)l[0] | ((unsigned)l[1] << 16);  lv0.y = (unsigned)l[2] | ((unsigned)l[3] << 16);
        lv0.z = (unsigned)l[4] | ((unsigned)l[5] << 16);  lv0.w = (unsigned)l[6] | ((unsigned)l[7] << 16);
        lv1.x = (unsigned)l[8] | ((unsigned)l[9] << 16);  lv1.y = (unsigned)l[10] | ((unsigned)l[11] << 16);
        lv1.z = (unsigned)l[12] | ((unsigned)l[13] << 16); lv1.w = (unsigned)l[14] | ((unsigned)l[15] << 16);
        size_t o = (size_t)(n0 + n) * K + k0 + kc;
        reinterpret_cast<uint4*>(&H[o])[0] = hv0; reinterpret_cast<uint4*>(&H[o])[1] = hv1;
        reinterpret_cast<uint4*>(&L[o])[0] = lv0; reinterpret_cast<uint4*>(&L[o])[1] = lv1;
    }
}

// ---- K converter: qkv K-part -> bf16 planes [bh][s][64] ----
__global__ __launch_bounds__(256) void cvt_kv_k_kernel(const float* __restrict__ qkv,
        unsigned short* __restrict__ Kh, unsigned short* __restrict__ Kl) {
    int t = blockIdx.x * 256 + threadIdx.x;
    int dg = t & 7;
    int s = (t >> 3) & (T - 1);
    int bh = t >> 14;                 // T*8 = 16384
    int b = bh / NH, h = bh % NH;
    const float* src = qkv + (size_t)(b * T + s) * C3 + 768 + h * 64 + dg * 8;
    float4 a0 = *reinterpret_cast<const float4*>(src);
    float4 a1 = *reinterpret_cast<const float4*>(src + 4);
    float f[8] = {a0.x, a0.y, a0.z, a0.w, a1.x, a1.y, a1.z, a1.w};
    unsigned short hh[8], ll[8];
    #pragma unroll
    for (int j = 0; j < 8; ++j) bf16split(f[j], hh[j], ll[j]);
    uint4 hv, lv;
    hv.x = (unsigned)hh[0] | ((unsigned)hh[1] << 16); hv.y = (unsigned)hh[2] | ((unsigned)hh[3] << 16);
    hv.z = (unsigned)hh[4] | ((unsigned)hh[5] << 16); hv.w = (unsigned)hh[6] | ((unsigned)hh[7] << 16);
    lv.x = (unsigned)ll[0] | ((unsigned)ll[1] << 16); lv.y = (unsigned)ll[2] | ((unsigned)ll[3] << 16);
    lv.z = (unsigned)ll[4] | ((unsigned)ll[5] << 16); lv.w = (unsigned)ll[6] | ((unsigned)ll[7] << 16);
    size_t o = ((size_t)bh * T + s) * 64 + dg * 8;
    *reinterpret_cast<uint4*>(&Kh[o]) = hv;
    *reinterpret_cast<uint4*>(&Kl[o]) = lv;
}

// ---- V converter (transposed): qkv V-part -> bf16 planes [bh][d][T] ----
__global__ __launch_bounds__(256) void cvt_kv_vt_kernel(const float* __restrict__ qkv,
        unsigned short* __restrict__ Vh, unsigned short* __restrict__ Vl) {
    __shared__ float tile[64][65];
    const int s0 = blockIdx.x * 64;
    const int bh = blockIdx.y;
    const int b = bh / NH, h = bh % NH;
    const int tid = threadIdx.x;
    {
        int r = tid >> 2, c0 = (tid & 3) * 16;
        const float* src = qkv + (size_t)(b * T + s0 + r) * C3 + 1536 + h * 64 + c0;
        #pragma unroll
        for (int u = 0; u < 4; ++u) {
            float4 w = *reinterpret_cast<const float4*>(src + u * 4);
            tile[r][c0 + u * 4 + 0] = w.x; tile[r][c0 + u * 4 + 1] = w.y;
            tile[r][c0 + u * 4 + 2] = w.z; tile[r][c0 + u * 4 + 3] = w.w;
        }
    }
    __syncthreads();
    {
        int d = tid >> 2, cs = (tid & 3) * 16;
        unsigned short hh[16], ll[16];
        #pragma unroll
        for (int j = 0; j < 16; ++j) bf16split(tile[cs + j][d], hh[j], ll[j]);
        uint4 hv0, hv1, lv0, lv1;
        hv0.x = (unsigned)hh[0] | ((unsigned)hh[1] << 16);  hv0.y = (unsigned)hh[2] | ((unsigned)hh[3] << 16);
        hv0.z = (unsigned)hh[4] | ((unsigned)hh[5] << 16);  hv0.w = (unsigned)hh[6] | ((unsigned)hh[7] << 16);
        hv1.x = (unsigned)hh[8] | ((unsigned)hh[9] << 16);  hv1.y = (unsigned)hh[10] | ((unsigned)hh[11] << 16);
        hv1.z = (unsigned)hh[12] | ((unsigned)hh[13] << 16); hv1.w = (unsigned)hh[14] | ((unsigned)hh[15] << 16);
        lv0.x = (unsigned)ll[0] | ((unsigned)ll[1] << 16);  lv0.y = (unsigned)ll[2] | ((unsigned)ll[3] << 16);
        lv0.z = (unsigned)ll[4] | ((unsigned)ll[5] << 16);  lv0.w = (unsigned)ll[6] | ((unsigned)ll[7] << 16);
        lv1.x = (unsigned)ll[8] | ((unsigned)ll[9] << 16);  lv1.y = (unsigned)ll[10] | ((unsigned)ll[11] << 16);
        lv1.z = (unsigned)ll[12] | ((unsigned)ll[13] << 16); lv1.w = (unsigned)ll[14] | ((unsigned)ll[15] << 16);
        size_t o = ((size_t)bh * 64 + d) * T + s0 + cs;
        reinterpret_cast<uint4*>(&Vh[o])[0] = hv0; reinterpret_cast<uint4*>(&Vh[o])[1] = hv1;
        reinterpret_cast<uint4*>(&Vl[o])[0] = lv0; reinterpret_cast<uint4*>(&Vl[o])[1] = lv1;
    }
}

// ---------------- split-bf16 MFMA GEMM: C = A*B + bias ----------------
#define LDST 40
__global__ __launch_bounds__(256) void gemm_mfma_kernel(
        const unsigned short* __restrict__ Ah, const unsigned short* __restrict__ Al,
        const unsigned short* __restrict__ Bh, const unsigned short* __restrict__ Bl,
        const float* __restrict__ bias, float* __restrict__ Cm,
        int M, int N, int K) {
    __shared__ unsigned short lA[2][128 * LDST];
    __shared__ unsigned short lB[2][128 * LDST];
    const int tid = threadIdx.x;
    const int bm = blockIdx.y * 128, bn = blockIdx.x * 128;
    const int lane = tid & 63, wid = tid >> 6;
    const int wr = wid >> 1, wc = wid & 1;
    f32x4 acc[4][4];
    #pragma unroll
    for (int i = 0; i < 4; ++i)
        #pragma unroll
        for (int j = 0; j < 4; ++j) acc[i][j] = (f32x4){0.f, 0.f, 0.f, 0.f};
    const int srow = tid >> 2, sk8 = (tid & 3) * 8;
    const int arb = wr * 64 + (lane & 15);
    const int brb = wc * 64 + (lane & 15);
    const int koff = (lane >> 4) * 8;
    for (int k0 = 0; k0 < K; k0 += 32) {
        __syncthreads();
        #pragma unroll
        for (int c = 0; c < 2; ++c) {
            int row = srow + 64 * c;
            uint4 va = *reinterpret_cast<const uint4*>(&Ah[(size_t)(bm + row) * K + k0 + sk8]);
            uint4 vb = *reinterpret_cast<const uint4*>(&Al[(size_t)(bm + row) * K + k0 + sk8]);
            uint4 vc = *reinterpret_cast<const uint4*>(&Bh[(size_t)(bn + row) * K + k0 + sk8]);
            uint4 vd = *reinterpret_cast<const uint4*>(&Bl[(size_t)(bn + row) * K + k0 + sk8]);
            *reinterpret_cast<uint4*>(&lA[0][row * LDST + sk8]) = va;
            *reinterpret_cast<uint4*>(&lA[1][row * LDST + sk8]) = vb;
            *reinterpret_cast<uint4*>(&lB[0][row * LDST + sk8]) = vc;
            *reinterpret_cast<uint4*>(&lB[1][row * LDST + sk8]) = vd;
        }
        __syncthreads();
        bf16x8 fa[2][4], fb[2][4];
        #pragma unroll
        for (int fi = 0; fi < 4; ++fi) {
            fa[0][fi] = *reinterpret_cast<const bf16x8*>(&lA[0][(arb + fi * 16) * LDST + koff]);
            fa[1][fi] = *reinterpret_cast<const bf16x8*>(&lA[1][(arb + fi * 16) * LDST + koff]);
            fb[0][fi] = *reinterpret_cast<const bf16x8*>(&lB[0][(brb + fi * 16) * LDST + koff]);
            fb[1][fi] = *reinterpret_cast<const bf16x8*>(&lB[1][(brb + fi * 16) * LDST + koff]);
        }
        #pragma unroll
        for (int fi = 0; fi < 4; ++fi)
            #pragma unroll
            for (int fj = 0; fj < 4; ++fj) {
                acc[fi][fj] = __builtin_amdgcn_mfma_f32_16x16x32_bf16(fa[0][fi], fb[0][fj], acc[fi][fj], 0, 0, 0);
                acc[fi][fj] = __builtin_amdgcn_mfma_f32_16x16x32_bf16(fa[0][fi], fb[1][fj], acc[fi][fj], 0, 0, 0);
                acc[fi][fj] = __builtin_amdgcn_mfma_f32_16x16x32_bf16(fa[1][fi], fb[0][fj], acc[fi][fj], 0, 0, 0);
            }
    }
    #pragma unroll
    for (int fj = 0; fj < 4; ++fj) {
        int col = bn + wc * 64 + fj * 16 + (lane & 15);
        float bv = bias[col];
        #pragma unroll
        for (int fi = 0; fi < 4; ++fi) {
            int row0 = bm + wr * 64 + fi * 16 + (lane >> 4) * 4;
            #pragma unroll
            for (int p = 0; p < 4; ++p)
                Cm[(size_t)(row0 + p) * N + col] = acc[fi][fj][p] + bv;
        }
    }
}

// ---------------- fp32 GEMM fallback (small ws) ----------------
__global__ __launch_bounds__(256) void gemm_bias_kernel(
        const float* __restrict__ A, const float* __restrict__ B,
        const float* __restrict__ bias, float* __restrict__ Cm,
        int M, int N, int K) {
    __shared__ float As[16][64];
    __shared__ float Bs[16][68];
    const int tid = threadIdx.x;
    const int ty = tid >> 4, tx = tid & 15;
    const int bm = blockIdx.y * 64, bn = blockIdx.x * 64;
    float acc[4][4] = {};
    for (int k0 = 0; k0 < K; k0 += 16) {
        {
            int r = tid >> 2;
            int kk = (tid & 3) * 4;
            float4 a = *reinterpret_cast<const float4*>(&A[(size_t)(bm + r) * K + k0 + kk]);
            As[kk + 0][r] = a.x; As[kk + 1][r] = a.y; As[kk + 2][r] = a.z; As[kk + 3][r] = a.w;
        }
        {
            int kk = tid >> 4;
            int c = (tid & 15) * 4;
            *reinterpret_cast<float4*>(&Bs[kk][c]) =
                *reinterpret_cast<const float4*>(&B[(size_t)(k0 + kk) * N + bn + c]);
        }
        __syncthreads();
        #pragma unroll
        for (int kk = 0; kk < 16; ++kk) {
            float4 a4 = *reinterpret_cast<const float4*>(&As[kk][ty * 4]);
            float4 b4 = *reinterpret_cast<const float4*>(&Bs[kk][tx * 4]);
            float av[4] = {a4.x, a4.y, a4.z, a4.w};
            float bv[4] = {b4.x, b4.y, b4.z, b4.w};
            #pragma unroll
            for (int i = 0; i < 4; ++i)
                #pragma unroll
                for (int j = 0; j < 4; ++j)
                    acc[i][j] = fmaf(av[i], bv[j], acc[i][j]);
        }
        __syncthreads();
    }
    #pragma unroll
    for (int i = 0; i < 4; ++i) {
        int row = bm + ty * 4 + i;
        #pragma unroll
        for (int j = 0; j < 4; ++j) {
            int col = bn + tx * 4 + j;
            Cm[(size_t)row * N + col] = acc[i][j] + bias[col];
        }
    }
}

// ---------------- S = masked relu of head-0 scores ----------------
__global__ __launch_bounds__(256) void s0_kernel(const float* __restrict__ qkv,
                                                 float* __restrict__ S) {
    const int kb = blockIdx.x * 64, qb = blockIdx.y * 64, b = blockIdx.z;
    const int tid = threadIdx.x, ty = tid >> 4, tx = tid & 15;
    float* Sb = S + (size_t)b * T * T;
    if (kb > qb) {
        #pragma unroll
        for (int i = 0; i < 4; ++i) {
            int row = qb + ty * 4 + i;
            float4 z = {0.f, 0.f, 0.f, 0.f};
            *reinterpret_cast<float4*>(&Sb[(size_t)row * T + kb + tx * 4]) = z;
        }
        return;
    }
    __shared__ float Qt[64][68];
    __shared__ float Kt[64][68];
    {
        int r = tid >> 2;
        int c0 = (tid & 3) * 16;
        const float* qrow = qkv + (size_t)(b * T + qb + r) * C3 + 0;
        const float* krow = qkv + (size_t)(b * T + kb + r) * C3 + 768;
        #pragma unroll
        for (int u = 0; u < 4; ++u) {
            float4 q4 = *reinterpret_cast<const float4*>(&qrow[c0 + u * 4]);
            float4 k4 = *reinterpret_cast<const float4*>(&krow[c0 + u * 4]);
            int d = c0 + u * 4;
            Qt[d + 0][r] = q4.x; Qt[d + 1][r] = q4.y; Qt[d + 2][r] = q4.z; Qt[d + 3][r] = q4.w;
            Kt[d + 0][r] = k4.x; Kt[d + 1][r] = k4.y; Kt[d + 2][r] = k4.z; Kt[d + 3][r] = k4.w;
        }
    }
    __syncthreads();
    float acc[4][4] = {};
    #pragma unroll
    for (int d = 0; d < 64; ++d) {
        float4 qv = *reinterpret_cast<const float4*>(&Qt[d][ty * 4]);
        float4 kv = *reinterpret_cast<const float4*>(&Kt[d][tx * 4]);
        float qa[4] = {qv.x, qv.y, qv.z, qv.w};
        float ka[4] = {kv.x, kv.y, kv.z, kv.w};
        #pragma unroll
        for (int i = 0; i < 4; ++i)
            #pragma unroll
            for (int j = 0; j < 4; ++j)
                acc[i][j] = fmaf(qa[i], ka[j], acc[i][j]);
    }
    #pragma unroll
    for (int i = 0; i < 4; ++i) {
        int t = qb + ty * 4 + i;
        float o[4];
        #pragma unroll
        for (int j = 0; j < 4; ++j) {
            int s = kb + tx * 4 + j;
            float v = acc[i][j] * 0.125f;
            o[j] = (s >= 1 && s < t) ? fmaxf(v, 0.0f) : 0.0f;
        }
        float4 o4 = {o[0], o[1], o[2], o[3]};
        *reinterpret_cast<float4*>(&Sb[(size_t)t * T + kb + tx * 4]) = o4;
    }
}

// ---------------- segmented scan: FF = cumsum_t(S) ----------------
__global__ __launch_bounds__(256) void colsum_kernel(const float* __restrict__ S,
                                                     float* __restrict__ Psum) {
    int s = blockIdx.x * 256 + threadIdx.x;
    int j = blockIdx.y, b = blockIdx.z;
    const float* Sb = S + (size_t)b * T * T;
    float sum = 0.f;
    for (int r = 0; r < 64; ++r) sum += Sb[(size_t)(j * 64 + r) * T + s];
    Psum[((size_t)b * 32 + j) * T + s] = sum;
}

__global__ __launch_bounds__(256) void scanseg_kernel(float* __restrict__ Psum) {
    int s = blockIdx.x * 256 + threadIdx.x;
    int b = blockIdx.y;
    float run = 0.f;
    for (int j = 0; j < 32; ++j) {
        size_t idx = ((size_t)b * 32 + j) * T + s;
        float v = Psum[idx];
        Psum[idx] = run;
        run += v;
    }
}

__global__ __launch_bounds__(256) void ffscan_kernel(float* __restrict__ S,
                                                     const float* __restrict__ Psum) {
    int s = blockIdx.x * 256 + threadIdx.x;
    int j = blockIdx.y, b = blockIdx.z;
    float run = Psum[((size_t)b * 32 + j) * T + s];
    float* Sb = S + (size_t)b * T * T;
    for (int r = 0; r < 64; ++r) {
        size_t idx = (size_t)(j * 64 + r) * T + s;
        run += Sb[idx];
        Sb[idx] = run;
    }
}

// ---------------- MFMA flash attention with -FF bias, split-K load balance ----------------
// K/V pre-converted to bf16 hi/lo planes (K: [bh][s][64], V^T: [bh][d][T]).
// Per wave: 16 q-rows; QK^T and PV each 24 MFMAs (3-product split-bf16).
// LDS: KP hi/lo (K, then reused for P) + Vt hi/lo = 36,864 B -> 4 blocks/CU.
#define FST 72   // LDS row stride (bf16), 144 B = 16B-aligned rows
__global__ __launch_bounds__(256) void flash_mfma_kernel(
        const float* __restrict__ qkv,
        const unsigned short* __restrict__ Kh, const unsigned short* __restrict__ Kl,
        const unsigned short* __restrict__ Vth, const unsigned short* __restrict__ Vtl,
        const float* __restrict__ FF, float* __restrict__ Y,
        float* __restrict__ PO, float* __restrict__ PML, int split) {
    const int hb = blockIdx.x;
    const int h = hb % NH, b = hb / NH;
    int qt, kt0, kt1, mode;
    if (split) {
        const int u = blockIdx.y;
        if (u < 16)      { qt = 16 + u; kt0 = 0;  kt1 = 16;     mode = 1; }
        else if (u < 32) { qt = 31 - u; kt0 = 0;  kt1 = qt + 1; mode = 0; }
        else             { qt = 63 - u; kt0 = 16; kt1 = qt + 1; mode = 2; }
    } else {
        qt = 31 - blockIdx.y; kt0 = 0; kt1 = qt + 1; mode = 0;
    }
    const int qb = qt * 64;
    const int tid = threadIdx.x;
    const int lane = tid & 63, w = tid >> 6;
    const int fr = lane & 15, fg = lane >> 4;
    __shared__ unsigned short KP[2][64 * FST];   // K hi/lo, then P hi/lo
    __shared__ unsigned short Vt[2][64 * FST];   // V^T hi/lo [d][s]

    // Q fragments -> registers (split bf16), once per block
    bf16x8 qh[2], ql[2];
    #pragma unroll
    for (int ks = 0; ks < 2; ++ks) {
        const float* qp = qkv + (size_t)(b * T + qb + w * 16 + fr) * C3 + h * 64 + ks * 32 + fg * 8;
        float4 q0 = *reinterpret_cast<const float4*>(qp);
        float4 q1 = *reinterpret_cast<const float4*>(qp + 4);
        float qf[8] = {q0.x, q0.y, q0.z, q0.w, q1.x, q1.y, q1.z, q1.w};
        #pragma unroll
        for (int e = 0; e < 8; ++e) {
            unsigned short hh, ll;
            bf16split(qf[e], hh, ll);
            qh[ks][e] = (short)hh; ql[ks][e] = (short)ll;
        }
    }

    float m[4], l[4];
    f32x4 Oacc[4];
    #pragma unroll
    for (int p = 0; p < 4; ++p) { m[p] = -1e30f; l[p] = 0.f; }
    #pragma unroll
    for (int fd = 0; fd < 4; ++fd) Oacc[fd] = (f32x4){0.f, 0.f, 0.f, 0.f};

    const float* FFb = FF + (size_t)b * T * T;
    const int sr = tid >> 2, sc0 = (tid & 3) * 16;   // staging coords

    for (int kt = kt0; kt < kt1; ++kt) {
        const int kb = kt * 64;
        __syncthreads();   // prev PV done reading KP(P)/Vt
        {   // stage K planes [s][d] and Vt planes [d][s] (pure b128 copies)
            const unsigned short* ksrc = Kh + ((size_t)hb * T + kb + sr) * 64 + sc0;
            const unsigned short* ksrl = Kl + ((size_t)hb * T + kb + sr) * 64 + sc0;
            const unsigned short* vsrc = Vth + ((size_t)hb * 64 + sr) * T + kb + sc0;
            const unsigned short* vsrl = Vtl + ((size_t)hb * 64 + sr) * T + kb + sc0;
            uint4 k0v = reinterpret_cast<const uint4*>(ksrc)[0];
            uint4 k1v = reinterpret_cast<const uint4*>(ksrc)[1];
            uint4 k2v = reinterpret_cast<const uint4*>(ksrl)[0];
            uint4 k3v = reinterpret_cast<const uint4*>(ksrl)[1];
            uint4 v0v = reinterpret_cast<const uint4*>(vsrc)[0];
            uint4 v1v = reinterpret_cast<const uint4*>(vsrc)[1];
            uint4 v2v = reinterpret_cast<const uint4*>(vsrl)[0];
            uint4 v3v = reinterpret_cast<const uint4*>(vsrl)[1];
            *reinterpret_cast<uint4*>(&KP[0][sr * FST + sc0 + 0]) = k0v;
            *reinterpret_cast<uint4*>(&KP[0][sr * FST + sc0 + 8]) = k1v;
            *reinterpret_cast<uint4*>(&KP[1][sr * FST + sc0 + 0]) = k2v;
            *reinterpret_cast<uint4*>(&KP[1][sr * FST + sc0 + 8]) = k3v;
            *reinterpret_cast<uint4*>(&Vt[0][sr * FST + sc0 + 0]) = v0v;
            *reinterpret_cast<uint4*>(&Vt[0][sr * FST + sc0 + 8]) = v1v;
            *reinterpret_cast<uint4*>(&Vt[1][sr * FST + sc0 + 0]) = v2v;
            *reinterpret_cast<uint4*>(&Vt[1][sr * FST + sc0 + 8]) = v3v;
        }
        __syncthreads();
        // ---- QK^T: S[16q x 64k] per wave, split-bf16 3-product ----
        f32x4 qk[4];
        #pragma unroll
        for (int fj = 0; fj < 4; ++fj) qk[fj] = (f32x4){0.f, 0.f, 0.f, 0.f};
        #pragma unroll
        for (int ks = 0; ks < 2; ++ks) {
            bf16x8 kbh[4], kbl[4];
            #pragma unroll
            for (int fj = 0; fj < 4; ++fj) {
                kbh[fj] = *reinterpret_cast<const bf16x8*>(&KP[0][(fj * 16 + fr) * FST + ks * 32 + fg * 8]);
                kbl[fj] = *reinterpret_cast<const bf16x8*>(&KP[1][(fj * 16 + fr) * FST + ks * 32 + fg * 8]);
            }
            #pragma unroll
            for (int fj = 0; fj < 4; ++fj) {
                qk[fj] = __builtin_amdgcn_mfma_f32_16x16x32_bf16(qh[ks], kbh[fj], qk[fj], 0, 0, 0);
                qk[fj] = __builtin_amdgcn_mfma_f32_16x16x32_bf16(qh[ks], kbl[fj], qk[fj], 0, 0, 0);
                qk[fj] = __builtin_amdgcn_mfma_f32_16x16x32_bf16(ql[ks], kbh[fj], qk[fj], 0, 0, 0);
            }
        }
        // ---- scores: *0.125 - FF, causal mask ----
        float sc[4][4];
        #pragma unroll
        for (int p = 0; p < 4; ++p) {
            int t = qb + w * 16 + fg * 4 + p;
            #pragma unroll
            for (int fj = 0; fj < 4; ++fj) {
                int s = kb + fj * 16 + fr;
                float v = qk[fj][p] * 0.125f - FFb[(size_t)t * T + s];
                sc[fj][p] = (s <= t) ? v : -1e30f;
            }
        }
        // ---- online softmax (row = (fg,p), reduce over fj + lanes fr) ----
        #pragma unroll
        for (int p = 0; p < 4; ++p) {
            float tm = fmaxf(fmaxf(sc[0][p], sc[1][p]), fmaxf(sc[2][p], sc[3][p]));
            tm = fmaxf(tm, __shfl_xor(tm, 1));
            tm = fmaxf(tm, __shfl_xor(tm, 2));
            tm = fmaxf(tm, __shfl_xor(tm, 4));
            tm = fmaxf(tm, __shfl_xor(tm, 8));
            float mn = fmaxf(m[p], tm);
            float scale = __expf(m[p] - mn);
            float rs = 0.f;
            #pragma unroll
            for (int fj = 0; fj < 4; ++fj) {
                float pe = __expf(sc[fj][p] - mn);
                sc[fj][p] = pe; rs += pe;
            }
            rs += __shfl_xor(rs, 1); rs += __shfl_xor(rs, 2);
            rs += __shfl_xor(rs, 4); rs += __shfl_xor(rs, 8);
            l[p] = l[p] * scale + rs;
            m[p] = mn;
            #pragma unroll
            for (int fd = 0; fd < 4; ++fd) Oacc[fd][p] *= scale;
        }
        __syncthreads();   // all QK reads of KP done before P overwrites
        // ---- write P (split bf16) into KP ----
        #pragma unroll
        for (int p = 0; p < 4; ++p) {
            int qrow = w * 16 + fg * 4 + p;
            #pragma unroll
            for (int fj = 0; fj < 4; ++fj) {
                unsigned short hh, ll;
                bf16split(sc[fj][p], hh, ll);
                KP[0][qrow * FST + fj * 16 + fr] = hh;
                KP[1][qrow * FST + fj * 16 + fr] = ll;
            }
        }
        __syncthreads();
        // ---- PV: O[16q x 64d] += P * V ----
        #pragma unroll
        for (int ks = 0; ks < 2; ++ks) {
            bf16x8 pah = *reinterpret_cast<const bf16x8*>(&KP[0][(w * 16 + fr) * FST + ks * 32 + fg * 8]);
            bf16x8 pal = *reinterpret_cast<const bf16x8*>(&KP[1][(w * 16 + fr) * FST + ks * 32 + fg * 8]);
            bf16x8 vbh[4], vbl[4];
            #pragma unroll
            for (int fd = 0; fd < 4; ++fd) {
                vbh[fd] = *reinterpret_cast<const bf16x8*>(&Vt[0][(fd * 16 + fr) * FST + ks * 32 + fg * 8]);
                vbl[fd] = *reinterpret_cast<const bf16x8*>(&Vt[1][(fd * 16 + fr) * FST + ks * 32 + fg * 8]);
            }
            #pragma unroll
            for (int fd = 0; fd < 4; ++fd) {
                Oacc[fd] = __builtin_amdgcn_mfma_f32_16x16x32_bf16(pah, vbh[fd], Oacc[fd], 0, 0, 0);
                Oacc[fd] = __builtin_amdgcn_mfma_f32_16x16x32_bf16(pah, vbl[fd], Oacc[fd], 0, 0, 0);
                Oacc[fd] = __builtin_amdgcn_mfma_f32_16x16x32_bf16(pal, vbh[fd], Oacc[fd], 0, 0, 0);
            }
        }
    }
    if (mode == 0) {
        #pragma unroll
        for (int p = 0; p < 4; ++p) {
            int t = qb + w * 16 + fg * 4 + p;
            float inv = 1.f / l[p];
            float* Yrow = Y + (size_t)(b * T + t) * CE + h * 64;
            #pragma unroll
            for (int fd = 0; fd < 4; ++fd)
                Yrow[fd * 16 + fr] = Oacc[fd][p] * inv;
        }
    } else {
        const int pidx = (b * NH + h) * 16 + (qt - 16);
        float* Ob  = PO  + (size_t)(mode - 1) * (NB * NH * 16 * 4096) + (size_t)pidx * 4096;
        float* mlb = PML + (size_t)(mode - 1) * (NB * NH * 16 * 128)  + (size_t)pidx * 128;
        #pragma unroll
        for (int p = 0; p < 4; ++p) {
            int rr = w * 16 + fg * 4 + p;
            #pragma unroll
            for (int fd = 0; fd < 4; ++fd)
                Ob[rr * 64 + fd * 16 + fr] = Oacc[fd][p];
            if (fr == 0) { mlb[rr] = m[p]; mlb[64 + rr] = l[p]; }
        }
    }
}

// ---------------- fp32 flash fallback (small ws) ----------------
__global__ __launch_bounds__(256) void flash_kernel(const float* __restrict__ qkv,
                                                    const float* __restrict__ FF,
                                                    float* __restrict__ Y,
                                                    float* __restrict__ PO,
                                                    float* __restrict__ PML,
                                                    int split) {
    const int hb = blockIdx.x;
    const int h = hb % NH, b = hb / NH;
    int qt, kt0, kt1, mode;
    if (split) {
        const int u = blockIdx.y;
        if (u < 16)      { qt = 16 + u; kt0 = 0;  kt1 = 16;     mode = 1; }
        else if (u < 32) { qt = 31 - u; kt0 = 0;  kt1 = qt + 1; mode = 0; }
        else             { qt = 63 - u; kt0 = 16; kt1 = qt + 1; mode = 2; }
    } else {
        qt = 31 - blockIdx.y; kt0 = 0; kt1 = qt + 1; mode = 0;
    }
    const int qb = qt * 64;
    const int tid = threadIdx.x, ty = tid >> 4, tx = tid & 15;
    __shared__ float Qt[64][68];
    __shared__ float KtPs[64][68];
    __shared__ float Vs[64][68];
    const int r = tid >> 2, c0 = (tid & 3) * 16;
    {
        const float* qrow = qkv + (size_t)(b * T + qb + r) * C3 + h * 64;
        #pragma unroll
        for (int u = 0; u < 4; ++u) {
            float4 q4 = *reinterpret_cast<const float4*>(&qrow[c0 + u * 4]);
            int d = c0 + u * 4;
            Qt[d + 0][r] = q4.x; Qt[d + 1][r] = q4.y; Qt[d + 2][r] = q4.z; Qt[d + 3][r] = q4.w;
        }
    }
    float m[4], l[4], O[4][4];
    #pragma unroll
    for (int i = 0; i < 4; ++i) {
        m[i] = -1e30f; l[i] = 0.f;
        #pragma unroll
        for (int j = 0; j < 4; ++j) O[i][j] = 0.f;
    }
    const float* FFb = FF + (size_t)b * T * T;
    for (int kt = kt0; kt < kt1; ++kt) {
        const int kb = kt * 64;
        __syncthreads();
        {
            const float* krow = qkv + (size_t)(b * T + kb + r) * C3 + 768 + h * 64;
            const float* vrow = qkv + (size_t)(b * T + kb + r) * C3 + 1536 + h * 64;
            #pragma unroll
            for (int u = 0; u < 4; ++u) {
                float4 k4 = *reinterpret_cast<const float4*>(&krow[c0 + u * 4]);
                int d = c0 + u * 4;
                KtPs[d + 0][r] = k4.x; KtPs[d + 1][r] = k4.y;
                KtPs[d + 2][r] = k4.z; KtPs[d + 3][r] = k4.w;
                *reinterpret_cast<float4*>(&Vs[r][c0 + u * 4]) =
                    *reinterpret_cast<const float4*>(&vrow[c0 + u * 4]);
            }
        }
        __syncthreads();
        float sc[4][4] = {};
        #pragma unroll
        for (int d = 0; d < 64; ++d) {
            float4 qv = *reinterpret_cast<const float4*>(&Qt[d][ty * 4]);
            float4 kv = *reinterpret_cast<const float4*>(&KtPs[d][tx * 4]);
            float qa[4] = {qv.x, qv.y, qv.z, qv.w};
            float ka[4] = {kv.x, kv.y, kv.z, kv.w};
            #pragma unroll
            for (int i = 0; i < 4; ++i)
                #pragma unroll
                for (int j = 0; j < 4; ++j)
                    sc[i][j] = fmaf(qa[i], ka[j], sc[i][j]);
        }
        #pragma unroll
        for (int i = 0; i < 4; ++i) {
            int t = qb + ty * 4 + i;
            float4 f4 = *reinterpret_cast<const float4*>(&FFb[(size_t)t * T + kb + tx * 4]);
            float fv[4] = {f4.x, f4.y, f4.z, f4.w};
            #pragma unroll
            for (int j = 0; j < 4; ++j) {
                int s = kb + tx * 4 + j;
                float v = sc[i][j] * 0.125f - fv[j];
                sc[i][j] = (s <= t) ? v : -1e30f;
            }
        }
        #pragma unroll
        for (int i = 0; i < 4; ++i) {
            float tm = fmaxf(fmaxf(sc[i][0], sc[i][1]), fmaxf(sc[i][2], sc[i][3]));
            tm = fmaxf(tm, __shfl_xor(tm, 1));
            tm = fmaxf(tm, __shfl_xor(tm, 2));
            tm = fmaxf(tm, __shfl_xor(tm, 4));
            tm = fmaxf(tm, __shfl_xor(tm, 8));
            float mn = fmaxf(m[i], tm);
            float scale = __expf(m[i] - mn);
            float rs = 0.f;
            #pragma unroll
            for (int j = 0; j < 4; ++j) {
                float p = __expf(sc[i][j] - mn);
                sc[i][j] = p; rs += p;
            }
            rs += __shfl_xor(rs, 1); rs += __shfl_xor(rs, 2);
            rs += __shfl_xor(rs, 4); rs += __shfl_xor(rs, 8);
            l[i] = l[i] * scale + rs;
            m[i] = mn;
            #pragma unroll
            for (int j = 0; j < 4; ++j) O[i][j] *= scale;
        }
        __syncthreads();
        #pragma unroll
        for (int i = 0; i < 4; ++i) {
            float4 p4 = {sc[i][0], sc[i][1], sc[i][2], sc[i][3]};
            *reinterpret_cast<float4*>(&KtPs[ty * 4 + i][tx * 4]) = p4;
        }
        __syncthreads();
        #pragma unroll
        for (int j4 = 0; j4 < 16; ++j4) {
            float pv[4][4];
            #pragma unroll
            for (int i = 0; i < 4; ++i) {
                float4 t4 = *reinterpret_cast<const float4*>(&KtPs[ty * 4 + i][j4 * 4]);
                pv[i][0] = t4.x; pv[i][1] = t4.y; pv[i][2] = t4.z; pv[i][3] = t4.w;
            }
            #pragma unroll
            for (int jj = 0; jj < 4; ++jj) {
                float4 v4 = *reinterpret_cast<const float4*>(&Vs[j4 * 4 + jj][tx * 4]);
                float vv[4] = {v4.x, v4.y, v4.z, v4.w};
                #pragma unroll
                for (int i = 0; i < 4; ++i)
                    #pragma unroll
                    for (int dd = 0; dd < 4; ++dd)
                        O[i][dd] = fmaf(pv[i][jj], vv[dd], O[i][dd]);
            }
        }
    }
    if (mode == 0) {
        #pragma unroll
        for (int i = 0; i < 4; ++i) {
            int t = qb + ty * 4 + i;
            float inv = 1.f / l[i];
            float4 o4 = {O[i][0] * inv, O[i][1] * inv, O[i][2] * inv, O[i][3] * inv};
            *reinterpret_cast<float4*>(&Y[(size_t)(b * T + t) * CE + h * 64 + tx * 4]) = o4;
        }
    } else {
        const int pidx = (b * NH + h) * 16 + (qt - 16);
        float* Ob  = PO  + (size_t)(mode - 1) * (NB * NH * 16 * 4096) + (size_t)pidx * 4096;
        float* mlb = PML + (size_t)(mode - 1) * (NB * NH * 16 * 128)  + (size_t)pidx * 128;
        #pragma unroll
        for (int i = 0; i < 4; ++i) {
            int rr = ty * 4 + i;
            float4 o4 = {O[i][0], O[i][1], O[i][2], O[i][3]};
            *reinterpret_cast<float4*>(&Ob[rr * 64 + tx * 4]) = o4;
            if (tx == 0) { mlb[rr] = m[i]; mlb[64 + rr] = l[i]; }
        }
    }
}

// ---------------- merge the two split-K partials for qt >= 16 ----------------
__global__ __launch_bounds__(256) void merge_kernel(const float* __restrict__ PO,
                                                    const float* __restrict__ PML,
                                                    float* __restrict__ Y) {
    const int p = blockIdx.x;
    const int q16 = p & 15;
    const int hb = p >> 4;
    const int h = hb % NH, b = hb / NH;
    const int qt = 16 + q16;
    const float* O0  = PO  + (size_t)p * 4096;
    const float* O1  = PO  + (size_t)(NB * NH * 16) * 4096 + (size_t)p * 4096;
    const float* ml0 = PML + (size_t)p * 128;
    const float* ml1 = PML + (size_t)(NB * NH * 16) * 128  + (size_t)p * 128;
    const int tid = threadIdx.x;
    const int r = tid >> 2, c0 = (tid & 3) * 16;
    float m0 = ml0[r], l0 = ml0[64 + r];
    float m1 = ml1[r], l1 = ml1[64 + r];
    float M  = fmaxf(m0, m1);
    float a0 = __expf(m0 - M), a1 = __expf(m1 - M);
    float inv = 1.f / (a0 * l0 + a1 * l1);
    const int t = qt * 64 + r;
    float* Yrow = Y + (size_t)(b * T + t) * CE + h * 64;
    #pragma unroll
    for (int u = 0; u < 4; ++u) {
        float4 x0 = *reinterpret_cast<const float4*>(&O0[r * 64 + c0 + u * 4]);
        float4 x1 = *reinterpret_cast<const float4*>(&O1[r * 64 + c0 + u * 4]);
        float4 y;
        y.x = (a0 * x0.x + a1 * x1.x) * inv;
        y.y = (a0 * x0.y + a1 * x1.y) * inv;
        y.z = (a0 * x0.z + a1 * x1.z) * inv;
        y.w = (a0 * x0.w + a1 * x1.w) * inv;
        *reinterpret_cast<float4*>(&Yrow[c0 + u * 4]) = y;
    }
}

extern "C" void kernel_launch(void* const* d_in, const int* in_sizes, int n_in,
                              void* d_out, int out_size, void* d_ws, size_t ws_size,
                              hipStream_t stream) {
    const float* x      = (const float*)d_in[0];
    const float* W_attn = (const float*)d_in[1];
    const float* b_attn = (const float*)d_in[2];
    const float* W_proj = (const float*)d_in[3];
    const float* b_proj = (const float*)d_in[4];
    float* out = (float*)d_out;

    char* ws = (char*)d_ws;
    const size_t QKV_BYTES = (size_t)NB * T * C3 * 4;       // 37,748,736
    const size_t S_BYTES   = (size_t)NB * T * T * 4;        // 33,554,432
    const size_t P_BYTES   = (size_t)NB * 32 * T * 4;       //    524,288
    const size_t Y_BYTES   = (size_t)NB * T * CE * 4;       // 12,582,912
    const size_t PO_BYTES  = (size_t)2 * NB * NH * 16 * 4096 * 4;  // 12,582,912
    const size_t PML_BYTES = (size_t)2 * NB * NH * 16 * 128 * 4;   //    393,216
    const size_t PLANE_X   = (size_t)NB * T * CE * 2;       // 6,291,456
    const size_t PLANE_WA  = (size_t)C3 * CE * 2;           // 3,538,944
    const size_t PLANE_WP  = (size_t)CE * CE * 2;           // 1,179,648
    const size_t PLANE_KV  = (size_t)NB * NH * T * 64 * 2;  // 6,291,456

    const size_t U_OFF  = QKV_BYTES + S_BYTES + P_BYTES + Y_BYTES;
    const size_t U_SIZE = PO_BYTES + PML_BYTES;
    const size_t W_OFF  = U_OFF + U_SIZE;
    const size_t KV_OFF = W_OFF + 2 * PLANE_WA + 2 * PLANE_WP;

    float* qkv  = (float*)ws;
    float* S    = (float*)(ws + QKV_BYTES);
    float* Psum = (float*)(ws + QKV_BYTES + S_BYTES);
    float* Yb   = (float*)(ws + QKV_BYTES + S_BYTES + P_BYTES);
    float* PO   = (float*)(ws + U_OFF);
    float* PML  = (float*)(ws + U_OFF + PO_BYTES);
    unsigned short* Xh  = (unsigned short*)(ws + U_OFF);    // overlaps PO (dead then)
    unsigned short* Xl  = (unsigned short*)(ws + U_OFF + PLANE_X);
    unsigned short* Yh  = Xh;
    unsigned short* Yl  = Xl;
    unsigned short* WAh = (unsigned short*)(ws + W_OFF);
    unsigned short* WAl = (unsigned short*)(ws + W_OFF + PLANE_WA);
    unsigned short* WPh = (unsigned short*)(ws + W_OFF + 2 * PLANE_WA);
    unsigned short* WPl = (unsigned short*)(ws + W_OFF + 2 * PLANE_WA + PLANE_WP);
    unsigned short* Khp = (unsigned short*)(ws + KV_OFF);
    unsigned short* Klp = (unsigned short*)(ws + KV_OFF + PLANE_KV);
    unsigned short* VTh = (unsigned short*)(ws + KV_OFF + 2 * PLANE_KV);
    unsigned short* VTl = (unsigned short*)(ws + KV_OFF + 3 * PLANE_KV);

    const size_t NEED_SPLIT = U_OFF + U_SIZE;
    const size_t NEED_MFMA  = KV_OFF;
    const size_t NEED_KV    = KV_OFF + 4 * PLANE_KV;
    const int split = (ws_size >= NEED_SPLIT) ? 1 : 0;
    const int mfma  = (ws_size >= NEED_MFMA) ? 1 : 0;
    const int kv    = (ws_size >= NEED_KV) ? 1 : 0;

    const int M = NB * T;  // 4096

    // 1) qkv = x @ W_attn + b_attn
    if (mfma) {
        cvt_split_T_kernel<<<dim3(C3 / 64, CE / 64), 256, 0, stream>>>(W_attn, WAh, WAl, CE, C3);
        cvt_split_T_kernel<<<dim3(CE / 64, CE / 64), 256, 0, stream>>>(W_proj, WPh, WPl, CE, CE);
        cvt_split_kernel<<<dim3((M * CE / 8) / 256), 256, 0, stream>>>(x, Xh, Xl);
        gemm_mfma_kernel<<<dim3(C3 / 128, M / 128), 256, 0, stream>>>(Xh, Xl, WAh, WAl, b_attn, qkv, M, C3, CE);
    } else {
        gemm_bias_kernel<<<dim3(C3 / 64, M / 64), 256, 0, stream>>>(x, W_attn, b_attn, qkv, M, C3, CE);
    }
    // 2) S = masked relu(head0 scores)
    s0_kernel<<<dim3(T / 64, T / 64, NB), 256, 0, stream>>>(qkv, S);
    // 3) FF = cumsum_t(S)  (segmented scan, in place)
    colsum_kernel<<<dim3(T / 256, 32, NB), 256, 0, stream>>>(S, Psum);
    scanseg_kernel<<<dim3(T / 256, NB), 256, 0, stream>>>(Psum);
    ffscan_kernel<<<dim3(T / 256, 32, NB), 256, 0, stream>>>(S, Psum);
    // 4) flash attention with bias -FF
    if (kv) {
        cvt_kv_k_kernel<<<dim3((NB * NH * T * 8) / 256), 256, 0, stream>>>(qkv, Khp, Klp);
        cvt_kv_vt_kernel<<<dim3(T / 64, NB * NH), 256, 0, stream>>>(qkv, VTh, VTl);
        if (split) {
            flash_mfma_kernel<<<dim3(NB * NH, 48), 256, 0, stream>>>(qkv, Khp, Klp, VTh, VTl, S, Yb, PO, PML, 1);
            merge_kernel<<<dim3(NB * NH * 16), 256, 0, stream>>>(PO, PML, Yb);
        } else {
            flash_mfma_kernel<<<dim3(NB * NH, 32), 256, 0, stream>>>(qkv, Khp, Klp, VTh, VTl, S, Yb, PO, PML, 0);
        }
    } else if (split) {
        flash_kernel<<<dim3(NB * NH, 48), 256, 0, stream>>>(qkv, S, Yb, PO, PML, 1);
        merge_kernel<<<dim3(NB * NH * 16), 256, 0, stream>>>(PO, PML, Yb);
    } else {
        flash_kernel<<<dim3(NB * NH, 32), 256, 0, stream>>>(qkv, S, Yb, PO, PML, 0);
    }
    // 5) out = Y @ W_proj + b_proj
    if (mfma) {
        cvt_split_kernel<<<dim3((M * CE / 8) / 256), 256, 0, stream>>>(Yb, Yh, Yl);
        gemm_mfma_kernel<<<dim3(CE / 128, M / 128), 256, 0, stream>>>(Yh, Yl, WPh, WPl, b_proj, out, M, CE, CE);
    } else {
        gemm_bias_kernel<<<dim3(CE / 64, M / 64), 256, 0, stream>>>(Yb, W_proj, b_proj, out, M, CE, CE);
    }
}